// Round 5
// baseline (220.205 us; speedup 1.0000x reference)
//
#include <hip/hip_runtime.h>

#define B_ 2
#define C_ 256
#define S_ 2304
#define DH_ 64
#define O3_ 1536
#define INNER_ 512
#define LOGSMAX 4.605170185988092f
#define LOG2E 1.4426950408889634f

typedef __attribute__((ext_vector_type(8))) short short8;
typedef __attribute__((ext_vector_type(4))) float f32x4;
typedef __attribute__((ext_vector_type(16))) float f32x16;
typedef __attribute__((ext_vector_type(4))) unsigned short us4;
typedef __bf16 bf16x8 __attribute__((ext_vector_type(8)));

__device__ __forceinline__ unsigned short f2bf(float f) {
  unsigned u = __builtin_bit_cast(unsigned, f);
  u += 0x7FFFu + ((u >> 16) & 1u);
  return (unsigned short)(u >> 16);
}
__device__ __forceinline__ float bf2f(unsigned short h) {
  return __builtin_bit_cast(float, (unsigned)h << 16);
}
__device__ __forceinline__ bf16x8 as_bf(short8 v) {
  return __builtin_bit_cast(bf16x8, v);
}
__device__ __forceinline__ float fexp2(float x) {
#if __has_builtin(__builtin_amdgcn_exp2f)
  return __builtin_amdgcn_exp2f(x);
#else
  return __expf(x * 0.6931471805599453f);
#endif
}
__device__ __forceinline__ float frcp(float x) {
#if __has_builtin(__builtin_amdgcn_rcpf)
  return __builtin_amdgcn_rcpf(x);
#else
  return 1.f / x;
#endif
}

// ---------------- K0: fused prep: x transpose + both weight converts ----------------
__global__ __launch_bounds__(256) void k_prep(const float* __restrict__ x,
                                              const float* __restrict__ w_in,
                                              const float* __restrict__ w_pw,
                                              unsigned short* __restrict__ xT,
                                              unsigned short* __restrict__ w_inb,
                                              unsigned short* __restrict__ w_pwb) {
  __shared__ float tile[64][65];
  int blk = blockIdx.x;
  int t = threadIdx.x;
  if (blk < 288) {  // transpose x [b][c][p] -> xT [b][p][c] bf16
    int p0 = (blk % 36) * 64, c0 = ((blk / 36) % 4) * 64, b = blk / 144;
    const float* xb = x + (size_t)b * C_ * S_;
#pragma unroll
    for (int i = 0; i < 16; i++) {
      int c = i * 4 + (t >> 6);
      int p = t & 63;
      tile[c][p] = xb[(size_t)(c0 + c) * S_ + p0 + p];
    }
    __syncthreads();
    unsigned short* xTb = xT + (size_t)b * S_ * C_;
#pragma unroll
    for (int i = 0; i < 16; i++) {
      int p = i * 4 + (t >> 6);
      int c = t & 63;
      xTb[(size_t)(p0 + p) * C_ + c0 + c] = f2bf(tile[c][p]);
    }
  } else if (blk < 288 + 1536) {
    int i = (blk - 288) * 256 + t;
    w_inb[i] = f2bf(w_in[i]);
  } else {
    int i = (blk - 1824) * 256 + t;
    w_pwb[i] = f2bf(w_pw[i]);
  }
}

// ---------------- K1/K5: GEMM  C[b][m][n] = sum_k A[m][k] * BT[b][n][k] ----------------
// 64x128 tile, 4 waves (each 64m x 32n). A: [M][K] shared across batch, BT: [b][N][K].
__global__ __launch_bounds__(256) void k_gemm(const unsigned short* __restrict__ A,
                                              const unsigned short* __restrict__ BT,
                                              void* __restrict__ outp,
                                              int M, int N, int K, int bf16out) {
  __shared__ __align__(16) unsigned short As[64][72];
  __shared__ __align__(16) unsigned short Bs[128][72];
  int t = threadIdx.x;
  int lane = t & 63, wv = t >> 6;
  int quad = lane >> 4, r15 = lane & 15;
  int m0 = blockIdx.y * 64, n0 = blockIdx.x * 128;
  int b = blockIdx.z;
  const unsigned short* BTb = BT + (size_t)b * N * K;

  f32x4 acc[4][2] = {};

  int srA = t >> 2, scA = (t & 3) * 16;   // A: 64 rows x 64 cols
  int srB = t >> 1, scB = (t & 1) * 32;   // B: 128 rows x 64 cols
  const unsigned short* ag = A + (size_t)(m0 + srA) * K + scA;
  const unsigned short* bg = BTb + (size_t)(n0 + srB) * K + scB;

  for (int k0 = 0; k0 < K; k0 += 64) {
    short8 a0 = *(const short8*)(ag + k0);
    short8 a1 = *(const short8*)(ag + k0 + 8);
    short8 b0 = *(const short8*)(bg + k0);
    short8 b1 = *(const short8*)(bg + k0 + 8);
    short8 b2 = *(const short8*)(bg + k0 + 16);
    short8 b3 = *(const short8*)(bg + k0 + 24);
    __syncthreads();
    *(short8*)&As[srA][scA] = a0;
    *(short8*)&As[srA][scA + 8] = a1;
    *(short8*)&Bs[srB][scB] = b0;
    *(short8*)&Bs[srB][scB + 8] = b1;
    *(short8*)&Bs[srB][scB + 16] = b2;
    *(short8*)&Bs[srB][scB + 24] = b3;
    __syncthreads();
#pragma unroll
    for (int ks = 0; ks < 2; ks++) {
      short8 af[4], bfr[2];
#pragma unroll
      for (int i = 0; i < 4; i++) af[i] = *(const short8*)&As[i * 16 + r15][ks * 32 + quad * 8];
#pragma unroll
      for (int j = 0; j < 2; j++) bfr[j] = *(const short8*)&Bs[wv * 32 + j * 16 + r15][ks * 32 + quad * 8];
#pragma unroll
      for (int i = 0; i < 4; i++)
#pragma unroll
        for (int j = 0; j < 2; j++)
          acc[i][j] = __builtin_amdgcn_mfma_f32_16x16x32_bf16(as_bf(af[i]), as_bf(bfr[j]), acc[i][j], 0, 0, 0);
    }
  }
  if (bf16out) {
    unsigned short* Cb = (unsigned short*)outp + (size_t)b * M * N;
#pragma unroll
    for (int i = 0; i < 4; i++)
#pragma unroll
      for (int j = 0; j < 2; j++)
#pragma unroll
        for (int rr = 0; rr < 4; rr++) {
          int row = m0 + i * 16 + quad * 4 + rr;
          int col = n0 + wv * 32 + j * 16 + r15;
          Cb[(size_t)row * N + col] = f2bf(acc[i][j][rr]);
        }
  } else {
    float* Cb = (float*)outp + (size_t)b * M * N;
#pragma unroll
    for (int i = 0; i < 4; i++)
#pragma unroll
      for (int j = 0; j < 2; j++)
#pragma unroll
        for (int rr = 0; rr < 4; rr++) {
          int row = m0 + i * 16 + quad * 4 + rr;
          int col = n0 + wv * 32 + j * 16 + r15;
          Cb[(size_t)row * N + col] = acc[i][j][rr];
        }
  }
}

// ---------------- K2: bias + l2norm q,k, v -> vT. 3 waves: seg 0=q,1=k,2=v ----------------
__global__ __launch_bounds__(192) void k_norm_qkv(const unsigned short* __restrict__ y,
                                                  const float* __restrict__ b_in,
                                                  const float* __restrict__ ss,
                                                  unsigned short* __restrict__ qn,
                                                  unsigned short* __restrict__ kn,
                                                  unsigned short* __restrict__ vT) {
  int t = threadIdx.x;
  int seg = t >> 6;
  int p = blockIdx.x * 64 + (t & 63);
  int bh = blockIdx.y;
  int b = bh >> 3, h = bh & 7;
  int obase = h * 192 + seg * 64;
  const unsigned short* yb = y + ((size_t)b * O3_ + obase) * S_ + p;
  const float* bb = b_in + obase;
  if (seg < 2) {
    float scale = (seg == 0) ? __expf(fminf(ss[h], LOGSMAX)) * LOG2E : 1.f;
    unsigned packed[32];
    float sumsq = 0.f;
#pragma unroll
    for (int d = 0; d < 64; d += 2) {
      float v0 = bf2f(yb[(size_t)d * S_]) + bb[d];
      float v1 = bf2f(yb[(size_t)(d + 1) * S_]) + bb[d + 1];
      sumsq += v0 * v0 + v1 * v1;
      packed[d >> 1] = (unsigned)f2bf(v0) | ((unsigned)f2bf(v1) << 16);
    }
    float inv = scale / fmaxf(sqrtf(sumsq), 1e-12f);
    unsigned short* dst = (seg == 0 ? qn : kn) + ((size_t)bh * S_ + p) * 64;
    unsigned outw[32];
#pragma unroll
    for (int i = 0; i < 32; i++) {
      float v0 = bf2f((unsigned short)(packed[i] & 0xffffu)) * inv;
      float v1 = bf2f((unsigned short)(packed[i] >> 16)) * inv;
      outw[i] = (unsigned)f2bf(v0) | ((unsigned)f2bf(v1) << 16);
    }
    uint4* d4 = (uint4*)dst;
#pragma unroll
    for (int i = 0; i < 8; i++)
      d4[i] = make_uint4(outw[4 * i], outw[4 * i + 1], outw[4 * i + 2], outw[4 * i + 3]);
  } else {
#pragma unroll
    for (int d = 0; d < 64; d++) {
      float v = bf2f(yb[(size_t)d * S_]) + bb[d];
      vT[((size_t)bh * DH_ + d) * S_ + p] = f2bf(v);
    }
  }
}

// ---------------- K3: attention, 32x32 MFMA, NO K/V LDS, NO barriers, split-K x2 ----------------
// K and V^T read directly from global (L2/XCD-local) as A-fragments. Only P goes through
// per-wave LDS. Fixed-shift softmax; UNNORMALIZED partial O (bf16) + l (fp32).
__global__ __launch_bounds__(128) void k_attn(const unsigned short* __restrict__ qn,
                                              const unsigned short* __restrict__ kn,
                                              const unsigned short* __restrict__ vT,
                                              const float* __restrict__ ss,
                                              unsigned short* __restrict__ attnp,
                                              float* __restrict__ lp) {
  __shared__ __align__(16) unsigned short Ps[2][32][76];   // per wave [q][key], stride 76 (2-way free)
  int t = threadIdx.x;
  int w = t >> 6;
  int lane = t & 63;
  int l31 = lane & 31, hi = lane >> 5;
  int bh = blockIdx.x;
  int q0 = blockIdx.y * 64 + w * 32;
  int split = blockIdx.z;
  int ktbase = split * 18;
  const unsigned short* qb = qn + (size_t)bh * S_ * DH_;
  const unsigned short* kb = kn + (size_t)bh * S_ * DH_;
  const unsigned short* vb = vT + (size_t)bh * DH_ * S_;
  float shift2 = __expf(fminf(ss[bh & 7], LOGSMAX)) * LOG2E;  // |s'| <= shift2

  // Q as B-fragment: n=query=l31, k(d) = ks*16 + hi*8 + j
  const unsigned short* qrow = qb + (size_t)(q0 + l31) * DH_ + hi * 8;
  short8 qf[4];
#pragma unroll
  for (int ks = 0; ks < 4; ks++) qf[ks] = *(const short8*)(qrow + ks * 16);

  const f32x16 z16 = {};
  f32x16 O0 = z16, O1 = z16;
  float l_part = 0.f;

  // K A-fragment bases: m(key) = mi*32 + l31, k(d) = ks*16 + hi*8 + j
  const unsigned short* kg0 = kb + ((size_t)(ktbase * 64) + l31) * DH_ + hi * 8;
  const unsigned short* kg1 = kg0 + (size_t)32 * DH_;
  // V A-fragment bases: m(d) = mi*32 + l31, k(key) = kt*64 + ks*16 + hi*8 + j
  const unsigned short* vg0 = vb + (size_t)l31 * S_ + ktbase * 64 + hi * 8;
  const unsigned short* vg1 = vg0 + (size_t)32 * S_;

  for (int i = 0; i < 18; i++) {
    size_t koff = (size_t)i * 64 * DH_;
    int voff = i * 64;
    // K fragments for this tile (8 x b128 from global, one 128B line per key row)
    short8 ka[4], kc[4];
#pragma unroll
    for (int ks = 0; ks < 4; ks++) {
      ka[ks] = *(const short8*)(kg0 + koff + ks * 16);
      kc[ks] = *(const short8*)(kg1 + koff + ks * 16);
    }
    // V fragments issued now so latency hides under S^T MFMA + softmax
    short8 va[4], vc[4];
#pragma unroll
    for (int ks = 0; ks < 4; ks++) {
      va[ks] = *(const short8*)(vg0 + voff + ks * 16);
      vc[ks] = *(const short8*)(vg1 + voff + ks * 16);
    }
    // S^T = K Q^T : A = K frags (m=key), B = Q regs (n=query)
    f32x16 sc0, sc1;
    sc0 = __builtin_amdgcn_mfma_f32_32x32x16_bf16(as_bf(ka[0]), as_bf(qf[0]), z16, 0, 0, 0);
    sc1 = __builtin_amdgcn_mfma_f32_32x32x16_bf16(as_bf(kc[0]), as_bf(qf[0]), z16, 0, 0, 0);
#pragma unroll
    for (int ks = 1; ks < 4; ks++) {
      sc0 = __builtin_amdgcn_mfma_f32_32x32x16_bf16(as_bf(ka[ks]), as_bf(qf[ks]), sc0, 0, 0, 0);
      sc1 = __builtin_amdgcn_mfma_f32_32x32x16_bf16(as_bf(kc[ks]), as_bf(qf[ks]), sc1, 0, 0, 0);
    }
    // exp2 numerator; P^T -> per-wave LDS as [q][key]
    float lsum = 0.f;
#pragma unroll
    for (int mt = 0; mt < 2; mt++) {
      const f32x16& s = mt ? sc1 : sc0;
#pragma unroll
      for (int g = 0; g < 4; g++) {
        float e0 = fexp2(s[g * 4 + 0] - shift2);
        float e1 = fexp2(s[g * 4 + 1] - shift2);
        float e2 = fexp2(s[g * 4 + 2] - shift2);
        float e3 = fexp2(s[g * 4 + 3] - shift2);
        lsum += (e0 + e1) + (e2 + e3);
        us4 pk = {f2bf(e0), f2bf(e1), f2bf(e2), f2bf(e3)};
        *(us4*)&Ps[w][l31][mt * 32 + g * 8 + hi * 4] = pk;
      }
    }
    l_part += lsum;
    // O^T += V^T P^T : A = V frags (m=d), B = P (n=query) — same-wave LDS, no barrier
#pragma unroll
    for (int ks = 0; ks < 4; ks++) {
      short8 pb = *(const short8*)&Ps[w][l31][ks * 16 + hi * 8];
      O0 = __builtin_amdgcn_mfma_f32_32x32x16_bf16(as_bf(va[ks]), as_bf(pb), O0, 0, 0, 0);
      O1 = __builtin_amdgcn_mfma_f32_32x32x16_bf16(as_bf(vc[ks]), as_bf(pb), O1, 0, 0, 0);
    }
  }
  float l = l_part + __shfl_xor(l_part, 32);
  if (hi == 0) lp[((size_t)(split * 16 + bh)) * S_ + q0 + l31] = l;
  unsigned short* orow = attnp + (((size_t)(split * 16 + bh)) * S_ + q0 + l31) * DH_;
#pragma unroll
  for (int mt = 0; mt < 2; mt++) {
    const f32x16& O = mt ? O1 : O0;
#pragma unroll
    for (int g = 0; g < 4; g++) {
      us4 o4 = {f2bf(O[g * 4 + 0]), f2bf(O[g * 4 + 1]), f2bf(O[g * 4 + 2]), f2bf(O[g * 4 + 3])};
      *(us4*)&orow[mt * 32 + g * 8 + hi * 4] = o4;
    }
  }
}

// ---------------- K4: depthwise 3x3 with split-combine + normalize ----------------
// attnp [split][bh][p][d] bf16 unnormalized, lp [split][bh][p] fp32 -> dwb [b][p][ch] bf16
__global__ __launch_bounds__(256) void k_dwconv(const unsigned short* __restrict__ attnp,
                                                const float* __restrict__ lp,
                                                const float* __restrict__ w_dw,
                                                unsigned short* __restrict__ dwb) {
  int t = threadIdx.x;
  int d = t & 63;
  int pj = t >> 6;
  int p = blockIdx.x * 4 + pj;
  int bh = blockIdx.y;
  int b = bh >> 3, h = bh & 7;
  int yy = p / 48, xx = p % 48;
  const unsigned short* a0 = attnp + (size_t)bh * S_ * DH_ + d;
  const unsigned short* a1 = attnp + ((size_t)(16 + bh)) * S_ * DH_ + d;
  const float* l0 = lp + (size_t)bh * S_;
  const float* l1 = lp + (size_t)(16 + bh) * S_;
  int ch = h * 64 + d;
  float w[9];
#pragma unroll
  for (int i = 0; i < 9; i++) w[i] = w_dw[ch * 9 + i];
  float acc = 0.f;
#pragma unroll
  for (int dy = -1; dy <= 1; dy++) {
    int y2 = yy + dy;
    if (y2 < 0 || y2 >= 48) continue;
#pragma unroll
    for (int dx = -1; dx <= 1; dx++) {
      int x2 = xx + dx;
      if (x2 < 0 || x2 >= 48) continue;
      int p2 = y2 * 48 + x2;  // wave-uniform
      float rl = frcp(l0[p2] + l1[p2]);
      float v = (bf2f(a0[(size_t)p2 * DH_]) + bf2f(a1[(size_t)p2 * DH_])) * rl;
      acc += v * w[(dy + 1) * 3 + dx + 1];
    }
  }
  dwb[((size_t)b * S_ + p) * INNER_ + ch] = f2bf(acc);
}

// ---------------- K6: channel LN + scales/shifts + final ----------------
__global__ __launch_bounds__(256) void k_ln_final(const float* __restrict__ pw,
                                                  const float* __restrict__ gamma,
                                                  const float* __restrict__ beta,
                                                  const float* __restrict__ x,
                                                  float* __restrict__ out) {
  __shared__ float s_sum[16][17];
  __shared__ float s_ss[16][17];
  int t = threadIdx.x;
  int pl = t & 15, cq = t >> 4;
  int gid = blockIdx.x;
  int b = gid / (S_ / 16);
  int p = (gid % (S_ / 16)) * 16 + pl;
  const float* pwb = pw + (size_t)b * INNER_ * S_;
  float sum = 0.f, sq = 0.f;
#pragma unroll
  for (int j = 0; j < 32; j++) {
    float v = pwb[(size_t)(cq * 32 + j) * S_ + p];
    sum += v;
    sq += v * v;
  }
  s_sum[cq][pl] = sum;
  s_ss[cq][pl] = sq;
  __syncthreads();
  float tot = 0.f, tss = 0.f;
#pragma unroll
  for (int i = 0; i < 16; i++) {
    tot += s_sum[i][pl];
    tss += s_ss[i][pl];
  }
  float mu = tot * (1.f / 512.f);
  float var = tss * (1.f / 512.f) - mu * mu;
  float rsig = rsqrtf(var + 1e-5f);
  const float* xb = x + (size_t)b * C_ * S_;
  float* ob = out + (size_t)b * C_ * S_;
#pragma unroll
  for (int j = 0; j < 16; j++) {
    int cc = cq * 16 + j;
    float scv = (pwb[(size_t)cc * S_ + p] - mu) * rsig * gamma[cc] + beta[cc];
    float shv = (pwb[(size_t)(cc + 256) * S_ + p] - mu) * rsig * gamma[cc + 256] + beta[cc + 256];
    ob[(size_t)cc * S_ + p] = shv + xb[(size_t)cc * S_ + p] * scv;
  }
}

extern "C" void kernel_launch(void* const* d_in, const int* in_sizes, int n_in,
                              void* d_out, int out_size, void* d_ws, size_t ws_size,
                              hipStream_t stream) {
  const float* x = (const float*)d_in[0];
  const float* w_in = (const float*)d_in[1];
  const float* b_in = (const float*)d_in[2];
  const float* ss = (const float*)d_in[3];
  const float* w_dw = (const float*)d_in[4];
  const float* w_pw = (const float*)d_in[5];
  const float* gamma = (const float*)d_in[6];
  const float* beta = (const float*)d_in[7];
  float* out = (float*)d_out;
  char* ws = (char*)d_ws;

  unsigned short* xT = (unsigned short*)(ws + 0);           // 2,359,296
  unsigned short* w_inb = (unsigned short*)(ws + 2359296);  // 786,432
  unsigned short* w_pwb = (unsigned short*)(ws + 3145728);  // 524,288
  unsigned short* qn = (unsigned short*)(ws + 3670016);     // 4,718,592
  unsigned short* kn = (unsigned short*)(ws + 8388608);     // 4,718,592
  unsigned short* vT = (unsigned short*)(ws + 13107200);    // 4,718,592
  unsigned short* dwb = (unsigned short*)(ws + 17825792);   // 4,718,592
  float* lp = (float*)(ws + 22544384);                      // 294,912  [2][16][2304] fp32
  char* big = ws + 22839296;                                // y / pw share (14,155,776)
  unsigned short* y = (unsigned short*)big;                 // bf16 [2][1536][2304] (dead after norm_qkv)
  float* pw = (float*)big;                                  // fp32 [2][512][2304] = 9,437,184
  unsigned short* attnp = (unsigned short*)(ws + 36995072); // bf16 [2][16][2304][64] = 9,437,184

  k_prep<<<2848, 256, 0, stream>>>(x, w_in, w_pw, xT, w_inb, w_pwb);
  k_gemm<<<dim3(18, 24, 2), 256, 0, stream>>>(w_inb, xT, y, O3_, S_, C_, 1);
  k_norm_qkv<<<dim3(36, 16), 192, 0, stream>>>(y, b_in, ss, qn, kn, vT);
  k_attn<<<dim3(16, 36, 2), 128, 0, stream>>>(qn, kn, vT, ss, attnp, lp);
  k_dwconv<<<dim3(576, 16), 256, 0, stream>>>(attnp, lp, w_dw, dwb);
  k_gemm<<<dim3(18, 8, 2), 256, 0, stream>>>(w_pwb, dwb, pw, INNER_, S_, INNER_, 0);
  k_ln_final<<<288, 256, 0, stream>>>(pw, gamma, beta, x, out);
}

// Round 6
// 189.405 us; speedup vs baseline: 1.1626x; 1.1626x over previous
//
#include <hip/hip_runtime.h>

#define B_ 2
#define C_ 256
#define S_ 2304
#define DH_ 64
#define O3_ 1536
#define INNER_ 512
#define LOGSMAX 4.605170185988092f
#define LOG2E 1.4426950408889634f

typedef __attribute__((ext_vector_type(8))) short short8;
typedef __attribute__((ext_vector_type(4))) float f32x4;
typedef __attribute__((ext_vector_type(16))) float f32x16;
typedef __attribute__((ext_vector_type(4))) unsigned short us4;
typedef __bf16 bf16x8 __attribute__((ext_vector_type(8)));

__device__ __forceinline__ unsigned short f2bf(float f) {
  unsigned u = __builtin_bit_cast(unsigned, f);
  u += 0x7FFFu + ((u >> 16) & 1u);
  return (unsigned short)(u >> 16);
}
__device__ __forceinline__ float bf2f(unsigned short h) {
  return __builtin_bit_cast(float, (unsigned)h << 16);
}
__device__ __forceinline__ bf16x8 as_bf(short8 v) {
  return __builtin_bit_cast(bf16x8, v);
}
__device__ __forceinline__ float fexp2(float x) {
#if __has_builtin(__builtin_amdgcn_exp2f)
  return __builtin_amdgcn_exp2f(x);
#else
  return __expf(x * 0.6931471805599453f);
#endif
}
__device__ __forceinline__ float frcp(float x) {
#if __has_builtin(__builtin_amdgcn_rcpf)
  return __builtin_amdgcn_rcpf(x);
#else
  return 1.f / x;
#endif
}

// ---------------- K0: fused prep: x transpose + both weight converts ----------------
__global__ __launch_bounds__(256) void k_prep(const float* __restrict__ x,
                                              const float* __restrict__ w_in,
                                              const float* __restrict__ w_pw,
                                              unsigned short* __restrict__ xT,
                                              unsigned short* __restrict__ w_inb,
                                              unsigned short* __restrict__ w_pwb) {
  __shared__ float tile[64][65];
  int blk = blockIdx.x;
  int t = threadIdx.x;
  if (blk < 288) {  // transpose x [b][c][p] -> xT [b][p][c] bf16
    int p0 = (blk % 36) * 64, c0 = ((blk / 36) % 4) * 64, b = blk / 144;
    const float* xb = x + (size_t)b * C_ * S_;
#pragma unroll
    for (int i = 0; i < 16; i++) {
      int c = i * 4 + (t >> 6);
      int p = t & 63;
      tile[c][p] = xb[(size_t)(c0 + c) * S_ + p0 + p];
    }
    __syncthreads();
    unsigned short* xTb = xT + (size_t)b * S_ * C_;
#pragma unroll
    for (int i = 0; i < 16; i++) {
      int p = i * 4 + (t >> 6);
      int c = t & 63;
      xTb[(size_t)(p0 + p) * C_ + c0 + c] = f2bf(tile[c][p]);
    }
  } else if (blk < 288 + 1536) {
    int i = (blk - 288) * 256 + t;
    w_inb[i] = f2bf(w_in[i]);
  } else {
    int i = (blk - 1824) * 256 + t;
    w_pwb[i] = f2bf(w_pw[i]);
  }
}

// ---------------- K1/K5: GEMM  C[b][m][n] = sum_k A[m][k] * BT[b][n][k] ----------------
// 64x128 tile, 4 waves (each 64m x 32n). A: [M][K] shared across batch, BT: [b][N][K].
__global__ __launch_bounds__(256) void k_gemm(const unsigned short* __restrict__ A,
                                              const unsigned short* __restrict__ BT,
                                              void* __restrict__ outp,
                                              int M, int N, int K, int bf16out) {
  __shared__ __align__(16) unsigned short As[64][72];
  __shared__ __align__(16) unsigned short Bs[128][72];
  int t = threadIdx.x;
  int lane = t & 63, wv = t >> 6;
  int quad = lane >> 4, r15 = lane & 15;
  int m0 = blockIdx.y * 64, n0 = blockIdx.x * 128;
  int b = blockIdx.z;
  const unsigned short* BTb = BT + (size_t)b * N * K;

  f32x4 acc[4][2] = {};

  int srA = t >> 2, scA = (t & 3) * 16;   // A: 64 rows x 64 cols
  int srB = t >> 1, scB = (t & 1) * 32;   // B: 128 rows x 64 cols
  const unsigned short* ag = A + (size_t)(m0 + srA) * K + scA;
  const unsigned short* bg = BTb + (size_t)(n0 + srB) * K + scB;

  for (int k0 = 0; k0 < K; k0 += 64) {
    short8 a0 = *(const short8*)(ag + k0);
    short8 a1 = *(const short8*)(ag + k0 + 8);
    short8 b0 = *(const short8*)(bg + k0);
    short8 b1 = *(const short8*)(bg + k0 + 8);
    short8 b2 = *(const short8*)(bg + k0 + 16);
    short8 b3 = *(const short8*)(bg + k0 + 24);
    __syncthreads();
    *(short8*)&As[srA][scA] = a0;
    *(short8*)&As[srA][scA + 8] = a1;
    *(short8*)&Bs[srB][scB] = b0;
    *(short8*)&Bs[srB][scB + 8] = b1;
    *(short8*)&Bs[srB][scB + 16] = b2;
    *(short8*)&Bs[srB][scB + 24] = b3;
    __syncthreads();
#pragma unroll
    for (int ks = 0; ks < 2; ks++) {
      short8 af[4], bfr[2];
#pragma unroll
      for (int i = 0; i < 4; i++) af[i] = *(const short8*)&As[i * 16 + r15][ks * 32 + quad * 8];
#pragma unroll
      for (int j = 0; j < 2; j++) bfr[j] = *(const short8*)&Bs[wv * 32 + j * 16 + r15][ks * 32 + quad * 8];
#pragma unroll
      for (int i = 0; i < 4; i++)
#pragma unroll
        for (int j = 0; j < 2; j++)
          acc[i][j] = __builtin_amdgcn_mfma_f32_16x16x32_bf16(as_bf(af[i]), as_bf(bfr[j]), acc[i][j], 0, 0, 0);
    }
  }
  if (bf16out) {
    unsigned short* Cb = (unsigned short*)outp + (size_t)b * M * N;
#pragma unroll
    for (int i = 0; i < 4; i++)
#pragma unroll
      for (int j = 0; j < 2; j++)
#pragma unroll
        for (int rr = 0; rr < 4; rr++) {
          int row = m0 + i * 16 + quad * 4 + rr;
          int col = n0 + wv * 32 + j * 16 + r15;
          Cb[(size_t)row * N + col] = f2bf(acc[i][j][rr]);
        }
  } else {
    float* Cb = (float*)outp + (size_t)b * M * N;
#pragma unroll
    for (int i = 0; i < 4; i++)
#pragma unroll
      for (int j = 0; j < 2; j++)
#pragma unroll
        for (int rr = 0; rr < 4; rr++) {
          int row = m0 + i * 16 + quad * 4 + rr;
          int col = n0 + wv * 32 + j * 16 + r15;
          Cb[(size_t)row * N + col] = acc[i][j][rr];
        }
  }
}

// ---------------- K2: bias + l2norm q,k, v -> vT. 3 waves: seg 0=q,1=k,2=v ----------------
__global__ __launch_bounds__(192) void k_norm_qkv(const unsigned short* __restrict__ y,
                                                  const float* __restrict__ b_in,
                                                  const float* __restrict__ ss,
                                                  unsigned short* __restrict__ qn,
                                                  unsigned short* __restrict__ kn,
                                                  unsigned short* __restrict__ vT) {
  int t = threadIdx.x;
  int seg = t >> 6;
  int p = blockIdx.x * 64 + (t & 63);
  int bh = blockIdx.y;
  int b = bh >> 3, h = bh & 7;
  int obase = h * 192 + seg * 64;
  const unsigned short* yb = y + ((size_t)b * O3_ + obase) * S_ + p;
  const float* bb = b_in + obase;
  if (seg < 2) {
    float scale = (seg == 0) ? __expf(fminf(ss[h], LOGSMAX)) * LOG2E : 1.f;
    unsigned packed[32];
    float sumsq = 0.f;
#pragma unroll
    for (int d = 0; d < 64; d += 2) {
      float v0 = bf2f(yb[(size_t)d * S_]) + bb[d];
      float v1 = bf2f(yb[(size_t)(d + 1) * S_]) + bb[d + 1];
      sumsq += v0 * v0 + v1 * v1;
      packed[d >> 1] = (unsigned)f2bf(v0) | ((unsigned)f2bf(v1) << 16);
    }
    float inv = scale / fmaxf(sqrtf(sumsq), 1e-12f);
    unsigned short* dst = (seg == 0 ? qn : kn) + ((size_t)bh * S_ + p) * 64;
    unsigned outw[32];
#pragma unroll
    for (int i = 0; i < 32; i++) {
      float v0 = bf2f((unsigned short)(packed[i] & 0xffffu)) * inv;
      float v1 = bf2f((unsigned short)(packed[i] >> 16)) * inv;
      outw[i] = (unsigned)f2bf(v0) | ((unsigned)f2bf(v1) << 16);
    }
    uint4* d4 = (uint4*)dst;
#pragma unroll
    for (int i = 0; i < 8; i++)
      d4[i] = make_uint4(outw[4 * i], outw[4 * i + 1], outw[4 * i + 2], outw[4 * i + 3]);
  } else {
#pragma unroll
    for (int d = 0; d < 64; d++) {
      float v = bf2f(yb[(size_t)d * S_]) + bb[d];
      vT[((size_t)bh * DH_ + d) * S_ + p] = f2bf(v);
    }
  }
}

// ---------------- K3: attention, 32x32 MFMA, 4 waves x 32q, LDS K/V shared, split-K x3 ----------------
// S^T = K Q^T; O^T = V^T P^T. Fixed-shift softmax; UNNORMALIZED partial O (bf16) + l (fp32).
__global__ __launch_bounds__(256) void k_attn(const unsigned short* __restrict__ qn,
                                              const unsigned short* __restrict__ kn,
                                              const unsigned short* __restrict__ vT,
                                              const float* __restrict__ ss,
                                              unsigned short* __restrict__ attnp,
                                              float* __restrict__ lp) {
  __shared__ __align__(16) unsigned short Ks[64][72];      // [key][d]
  __shared__ __align__(16) unsigned short Vs[64][72];      // [d][key]
  __shared__ __align__(16) unsigned short Ps[4][32][76];   // per wave [q][key]
  int t = threadIdx.x;
  int w = t >> 6;
  int lane = t & 63;
  int l31 = lane & 31, hi = lane >> 5;
  int bh = blockIdx.x;
  int q0 = blockIdx.y * 128 + w * 32;
  int split = blockIdx.z;
  int ktbase = split * 12;
  const unsigned short* qb = qn + (size_t)bh * S_ * DH_;
  const unsigned short* kb = kn + (size_t)bh * S_ * DH_;
  const unsigned short* vb = vT + (size_t)bh * DH_ * S_;
  float shift2 = __expf(fminf(ss[bh & 7], LOGSMAX)) * LOG2E;  // |s'| <= shift2

  // Q as B-fragment: n=query=l31, k(d) = ks*16 + hi*8 + j
  const unsigned short* qrow = qb + (size_t)(q0 + l31) * DH_ + hi * 8;
  short8 qf[4];
#pragma unroll
  for (int ks = 0; ks < 4; ks++) qf[ks] = *(const short8*)(qrow + ks * 16);

  const f32x16 z16 = {};
  f32x16 O0 = z16, O1 = z16;
  float l_part = 0.f;

  // staging: 256 threads cover 64x64 K tile + 64x64 V tile, 16 shorts each
  int srow = t >> 2;          // 0..63
  int scol = (t & 3) * 16;    // 0,16,32,48
  const unsigned short* kg = kb + ((size_t)(ktbase * 64) + srow) * DH_ + scol;
  const unsigned short* vg = vb + (size_t)srow * S_ + ktbase * 64 + scol;

  // preload first tile into regs
  short8 kr0 = *(const short8*)(kg);
  short8 kr1 = *(const short8*)(kg + 8);
  short8 vr0 = *(const short8*)(vg);
  short8 vr1 = *(const short8*)(vg + 8);

  for (int i = 0; i < 12; i++) {
    __syncthreads();
    *(short8*)&Ks[srow][scol] = kr0;
    *(short8*)&Ks[srow][scol + 8] = kr1;
    *(short8*)&Vs[srow][scol] = vr0;
    *(short8*)&Vs[srow][scol + 8] = vr1;
    __syncthreads();
    if (i < 11) {  // prefetch next tile; latency hides under compute below
      size_t koff = (size_t)(i + 1) * 64 * DH_;
      int voff = (i + 1) * 64;
      kr0 = *(const short8*)(kg + koff);
      kr1 = *(const short8*)(kg + koff + 8);
      vr0 = *(const short8*)(vg + voff);
      vr1 = *(const short8*)(vg + voff + 8);
    }
    // S^T = K Q^T : A = K-tile (m=key), B = Q regs (n=query)
    f32x16 sc0, sc1;
    {
      short8 a0 = *(const short8*)&Ks[l31][hi * 8];
      short8 a1 = *(const short8*)&Ks[32 + l31][hi * 8];
      sc0 = __builtin_amdgcn_mfma_f32_32x32x16_bf16(as_bf(a0), as_bf(qf[0]), z16, 0, 0, 0);
      sc1 = __builtin_amdgcn_mfma_f32_32x32x16_bf16(as_bf(a1), as_bf(qf[0]), z16, 0, 0, 0);
    }
#pragma unroll
    for (int ks = 1; ks < 4; ks++) {
      short8 a0 = *(const short8*)&Ks[l31][ks * 16 + hi * 8];
      short8 a1 = *(const short8*)&Ks[32 + l31][ks * 16 + hi * 8];
      sc0 = __builtin_amdgcn_mfma_f32_32x32x16_bf16(as_bf(a0), as_bf(qf[ks]), sc0, 0, 0, 0);
      sc1 = __builtin_amdgcn_mfma_f32_32x32x16_bf16(as_bf(a1), as_bf(qf[ks]), sc1, 0, 0, 0);
    }
    // exp2 numerator; P^T -> per-wave LDS as [q][key]
    float lsum = 0.f;
#pragma unroll
    for (int mt = 0; mt < 2; mt++) {
      const f32x16& s = mt ? sc1 : sc0;
#pragma unroll
      for (int g = 0; g < 4; g++) {
        float e0 = fexp2(s[g * 4 + 0] - shift2);
        float e1 = fexp2(s[g * 4 + 1] - shift2);
        float e2 = fexp2(s[g * 4 + 2] - shift2);
        float e3 = fexp2(s[g * 4 + 3] - shift2);
        lsum += (e0 + e1) + (e2 + e3);
        us4 pk = {f2bf(e0), f2bf(e1), f2bf(e2), f2bf(e3)};
        *(us4*)&Ps[w][l31][mt * 32 + g * 8 + hi * 4] = pk;
      }
    }
    l_part += lsum;
    // O^T += V^T P^T : A = V-tile (m=d), B = P (n=query) — same-wave LDS, no barrier
#pragma unroll
    for (int ks = 0; ks < 4; ks++) {
      short8 pb = *(const short8*)&Ps[w][l31][ks * 16 + hi * 8];
      short8 va0 = *(const short8*)&Vs[l31][ks * 16 + hi * 8];
      short8 va1 = *(const short8*)&Vs[32 + l31][ks * 16 + hi * 8];
      O0 = __builtin_amdgcn_mfma_f32_32x32x16_bf16(as_bf(va0), as_bf(pb), O0, 0, 0, 0);
      O1 = __builtin_amdgcn_mfma_f32_32x32x16_bf16(as_bf(va1), as_bf(pb), O1, 0, 0, 0);
    }
  }
  float l = l_part + __shfl_xor(l_part, 32);
  if (hi == 0) lp[((size_t)(split * 16 + bh)) * S_ + q0 + l31] = l;
  unsigned short* orow = attnp + (((size_t)(split * 16 + bh)) * S_ + q0 + l31) * DH_;
#pragma unroll
  for (int mt = 0; mt < 2; mt++) {
    const f32x16& O = mt ? O1 : O0;
#pragma unroll
    for (int g = 0; g < 4; g++) {
      us4 o4 = {f2bf(O[g * 4 + 0]), f2bf(O[g * 4 + 1]), f2bf(O[g * 4 + 2]), f2bf(O[g * 4 + 3])};
      *(us4*)&orow[mt * 32 + g * 8 + hi * 4] = o4;
    }
  }
}

// ---------------- K4: depthwise 3x3 with 3-way split-combine + normalize ----------------
__global__ __launch_bounds__(256) void k_dwconv(const unsigned short* __restrict__ attnp,
                                                const float* __restrict__ lp,
                                                const float* __restrict__ w_dw,
                                                unsigned short* __restrict__ dwb) {
  int t = threadIdx.x;
  int d = t & 63;
  int pj = t >> 6;
  int p = blockIdx.x * 4 + pj;
  int bh = blockIdx.y;
  int b = bh >> 3, h = bh & 7;
  int yy = p / 48, xx = p % 48;
  const unsigned short* a0 = attnp + (size_t)bh * S_ * DH_ + d;
  const unsigned short* a1 = attnp + ((size_t)(16 + bh)) * S_ * DH_ + d;
  const unsigned short* a2 = attnp + ((size_t)(32 + bh)) * S_ * DH_ + d;
  const float* l0 = lp + (size_t)bh * S_;
  const float* l1 = lp + (size_t)(16 + bh) * S_;
  const float* l2 = lp + (size_t)(32 + bh) * S_;
  int ch = h * 64 + d;
  float w[9];
#pragma unroll
  for (int i = 0; i < 9; i++) w[i] = w_dw[ch * 9 + i];
  float acc = 0.f;
#pragma unroll
  for (int dy = -1; dy <= 1; dy++) {
    int y2 = yy + dy;
    if (y2 < 0 || y2 >= 48) continue;
#pragma unroll
    for (int dx = -1; dx <= 1; dx++) {
      int x2 = xx + dx;
      if (x2 < 0 || x2 >= 48) continue;
      int p2 = y2 * 48 + x2;  // wave-uniform
      float rl = frcp(l0[p2] + l1[p2] + l2[p2]);
      float v = (bf2f(a0[(size_t)p2 * DH_]) + bf2f(a1[(size_t)p2 * DH_]) + bf2f(a2[(size_t)p2 * DH_])) * rl;
      acc += v * w[(dy + 1) * 3 + dx + 1];
    }
  }
  dwb[((size_t)b * S_ + p) * INNER_ + ch] = f2bf(acc);
}

// ---------------- K6: channel LN + scales/shifts + final (8-pos chunks) ----------------
__global__ __launch_bounds__(256) void k_ln_final(const float* __restrict__ pw,
                                                  const float* __restrict__ gamma,
                                                  const float* __restrict__ beta,
                                                  const float* __restrict__ x,
                                                  float* __restrict__ out) {
  __shared__ float s_sum[32][9];
  __shared__ float s_ss[32][9];
  int t = threadIdx.x;
  int pl = t & 7, cq = t >> 3;   // 8 positions x 32 channel-groups
  int gid = blockIdx.x;
  int b = gid / (S_ / 8);
  int p = (gid % (S_ / 8)) * 8 + pl;
  const float* pwb = pw + (size_t)b * INNER_ * S_;
  float sum = 0.f, sq = 0.f;
#pragma unroll
  for (int j = 0; j < 16; j++) {
    float v = pwb[(size_t)(cq * 16 + j) * S_ + p];
    sum += v;
    sq += v * v;
  }
  s_sum[cq][pl] = sum;
  s_ss[cq][pl] = sq;
  __syncthreads();
  float tot = 0.f, tss = 0.f;
#pragma unroll
  for (int i = 0; i < 32; i++) {
    tot += s_sum[i][pl];
    tss += s_ss[i][pl];
  }
  float mu = tot * (1.f / 512.f);
  float var = tss * (1.f / 512.f) - mu * mu;
  float rsig = rsqrtf(var + 1e-5f);
  const float* xb = x + (size_t)b * C_ * S_;
  float* ob = out + (size_t)b * C_ * S_;
#pragma unroll
  for (int j = 0; j < 8; j++) {
    int cc = cq * 8 + j;
    float scv = (pwb[(size_t)cc * S_ + p] - mu) * rsig * gamma[cc] + beta[cc];
    float shv = (pwb[(size_t)(cc + 256) * S_ + p] - mu) * rsig * gamma[cc + 256] + beta[cc + 256];
    ob[(size_t)cc * S_ + p] = shv + xb[(size_t)cc * S_ + p] * scv;
  }
}

extern "C" void kernel_launch(void* const* d_in, const int* in_sizes, int n_in,
                              void* d_out, int out_size, void* d_ws, size_t ws_size,
                              hipStream_t stream) {
  const float* x = (const float*)d_in[0];
  const float* w_in = (const float*)d_in[1];
  const float* b_in = (const float*)d_in[2];
  const float* ss = (const float*)d_in[3];
  const float* w_dw = (const float*)d_in[4];
  const float* w_pw = (const float*)d_in[5];
  const float* gamma = (const float*)d_in[6];
  const float* beta = (const float*)d_in[7];
  float* out = (float*)d_out;
  char* ws = (char*)d_ws;

  unsigned short* xT = (unsigned short*)(ws + 0);           // 2,359,296
  unsigned short* w_inb = (unsigned short*)(ws + 2359296);  // 786,432
  unsigned short* w_pwb = (unsigned short*)(ws + 3145728);  // 524,288
  unsigned short* qn = (unsigned short*)(ws + 3670016);     // 4,718,592
  unsigned short* kn = (unsigned short*)(ws + 8388608);     // 4,718,592
  unsigned short* vT = (unsigned short*)(ws + 13107200);    // 4,718,592
  unsigned short* dwb = (unsigned short*)(ws + 17825792);   // 4,718,592
  float* lp = (float*)(ws + 22544384);                      // 442,368  [3][16][2304] fp32
  char* regionA = ws + 22986752;                            // 14,155,776 shared: y then attnp
  unsigned short* y = (unsigned short*)regionA;             // bf16 [2][1536][2304], dead after norm_qkv
  unsigned short* attnp = (unsigned short*)regionA;         // bf16 [3][16][2304][64], dead after dwconv
  float* pw = (float*)(ws + 37142528);                      // fp32 [2][512][2304] = 9,437,184

  k_prep<<<2848, 256, 0, stream>>>(x, w_in, w_pw, xT, w_inb, w_pwb);
  k_gemm<<<dim3(18, 24, 2), 256, 0, stream>>>(w_inb, xT, y, O3_, S_, C_, 1);
  k_norm_qkv<<<dim3(36, 16), 192, 0, stream>>>(y, b_in, ss, qn, kn, vT);
  k_attn<<<dim3(16, 18, 3), 256, 0, stream>>>(qn, kn, vT, ss, attnp, lp);
  k_dwconv<<<dim3(576, 16), 256, 0, stream>>>(attnp, lp, w_dw, dwb);
  k_gemm<<<dim3(18, 8, 2), 256, 0, stream>>>(w_pwb, dwb, pw, INNER_, S_, INNER_, 0);
  k_ln_final<<<576, 256, 0, stream>>>(pw, gamma, beta, x, out);
}

// Round 7
// 182.214 us; speedup vs baseline: 1.2085x; 1.0395x over previous
//
#include <hip/hip_runtime.h>

#define B_ 2
#define C_ 256
#define S_ 2304
#define DH_ 64
#define O3_ 1536
#define INNER_ 512
#define LOGSMAX 4.605170185988092f
#define LOG2E 1.4426950408889634f

typedef __attribute__((ext_vector_type(8))) short short8;
typedef __attribute__((ext_vector_type(4))) float f32x4;
typedef __attribute__((ext_vector_type(16))) float f32x16;
typedef __attribute__((ext_vector_type(4))) unsigned short us4;
typedef __attribute__((ext_vector_type(2))) unsigned u32x2;
typedef __attribute__((ext_vector_type(4))) unsigned u32x4;
typedef __bf16 bf16x8 __attribute__((ext_vector_type(8)));

__device__ __forceinline__ unsigned short f2bf(float f) {
  unsigned u = __builtin_bit_cast(unsigned, f);
  u += 0x7FFFu + ((u >> 16) & 1u);
  return (unsigned short)(u >> 16);
}
__device__ __forceinline__ float bf2f(unsigned short h) {
  return __builtin_bit_cast(float, (unsigned)h << 16);
}
__device__ __forceinline__ bf16x8 as_bf(short8 v) {
  return __builtin_bit_cast(bf16x8, v);
}
__device__ __forceinline__ float fexp2(float x) {
#if __has_builtin(__builtin_amdgcn_exp2f)
  return __builtin_amdgcn_exp2f(x);
#else
  return __expf(x * 0.6931471805599453f);
#endif
}
__device__ __forceinline__ float frcp(float x) {
#if __has_builtin(__builtin_amdgcn_rcpf)
  return __builtin_amdgcn_rcpf(x);
#else
  return 1.f / x;
#endif
}
// pack hi16 of two fp32 bit-patterns: (hi16(b)<<16)|hi16(a) — 1 v_perm_b32
__device__ __forceinline__ unsigned pack_hi16(unsigned b, unsigned a) {
  return __builtin_amdgcn_perm(b, a, 0x07060302u);
}
// pack lo16: (lo16(b)<<16)|lo16(a)
__device__ __forceinline__ unsigned pack_lo16(unsigned b, unsigned a) {
  return __builtin_amdgcn_perm(b, a, 0x05040100u);
}

// ---------------- K0: fused prep: x transpose + both weight converts ----------------
__global__ __launch_bounds__(256) void k_prep(const float* __restrict__ x,
                                              const float* __restrict__ w_in,
                                              const float* __restrict__ w_pw,
                                              unsigned short* __restrict__ xT,
                                              unsigned short* __restrict__ w_inb,
                                              unsigned short* __restrict__ w_pwb) {
  __shared__ float tile[64][65];
  int blk = blockIdx.x;
  int t = threadIdx.x;
  if (blk < 288) {  // transpose x [b][c][p] -> xT [b][p][c] bf16
    int p0 = (blk % 36) * 64, c0 = ((blk / 36) % 4) * 64, b = blk / 144;
    const float* xb = x + (size_t)b * C_ * S_;
#pragma unroll
    for (int i = 0; i < 16; i++) {
      int c = i * 4 + (t >> 6);
      int p = t & 63;
      tile[c][p] = xb[(size_t)(c0 + c) * S_ + p0 + p];
    }
    __syncthreads();
    unsigned short* xTb = xT + (size_t)b * S_ * C_;
#pragma unroll
    for (int i = 0; i < 16; i++) {
      int p = i * 4 + (t >> 6);
      int c = t & 63;
      xTb[(size_t)(p0 + p) * C_ + c0 + c] = f2bf(tile[c][p]);
    }
  } else if (blk < 288 + 1536) {
    int i = (blk - 288) * 256 + t;
    w_inb[i] = f2bf(w_in[i]);
  } else {
    int i = (blk - 1824) * 256 + t;
    w_pwb[i] = f2bf(w_pw[i]);
  }
}

// ---------------- K1: proj_in GEMM with fused bias + l2norm + scale epilogue ----------------
// 64x128 tile; M-tile 64 == one (head, q/k/v-seg) channel group. Writes qn/kn/vv [bh][p][64].
__global__ __launch_bounds__(256) void k_gemm_qkv(const unsigned short* __restrict__ A,
                                                  const unsigned short* __restrict__ BT,
                                                  const float* __restrict__ b_in,
                                                  const float* __restrict__ ss,
                                                  unsigned short* __restrict__ qn,
                                                  unsigned short* __restrict__ kn,
                                                  unsigned short* __restrict__ vv) {
  __shared__ __align__(16) unsigned short As[64][72];
  __shared__ __align__(16) unsigned short Bs[128][72];
  int t = threadIdx.x;
  int lane = t & 63, wv = t >> 6;
  int quad = lane >> 4, r15 = lane & 15;
  int by = blockIdx.y;
  int m0 = by * 64, n0 = blockIdx.x * 128;
  int b = blockIdx.z;
  const unsigned short* BTb = BT + (size_t)b * S_ * C_;

  f32x4 acc[4][2] = {};

  int srA = t >> 2, scA = (t & 3) * 16;
  int srB = t >> 1, scB = (t & 1) * 32;
  const unsigned short* ag = A + (size_t)(m0 + srA) * C_ + scA;
  const unsigned short* bg = BTb + (size_t)(n0 + srB) * C_ + scB;

  for (int k0 = 0; k0 < C_; k0 += 64) {
    short8 a0 = *(const short8*)(ag + k0);
    short8 a1 = *(const short8*)(ag + k0 + 8);
    short8 b0 = *(const short8*)(bg + k0);
    short8 b1 = *(const short8*)(bg + k0 + 8);
    short8 b2 = *(const short8*)(bg + k0 + 16);
    short8 b3 = *(const short8*)(bg + k0 + 24);
    __syncthreads();
    *(short8*)&As[srA][scA] = a0;
    *(short8*)&As[srA][scA + 8] = a1;
    *(short8*)&Bs[srB][scB] = b0;
    *(short8*)&Bs[srB][scB + 8] = b1;
    *(short8*)&Bs[srB][scB + 16] = b2;
    *(short8*)&Bs[srB][scB + 24] = b3;
    __syncthreads();
#pragma unroll
    for (int ks = 0; ks < 2; ks++) {
      short8 af[4], bfr[2];
#pragma unroll
      for (int i = 0; i < 4; i++) af[i] = *(const short8*)&As[i * 16 + r15][ks * 32 + quad * 8];
#pragma unroll
      for (int j = 0; j < 2; j++) bfr[j] = *(const short8*)&Bs[wv * 32 + j * 16 + r15][ks * 32 + quad * 8];
#pragma unroll
      for (int i = 0; i < 4; i++)
#pragma unroll
        for (int j = 0; j < 2; j++)
          acc[i][j] = __builtin_amdgcn_mfma_f32_16x16x32_bf16(as_bf(af[i]), as_bf(bfr[j]), acc[i][j], 0, 0, 0);
    }
  }

  // epilogue: bias add, per-position l2norm (q/k), scale (q), store bf16
  int h = by / 3, seg = by - h * 3;
  int bh = b * 8 + h;
  f32x4 bi[4];
#pragma unroll
  for (int i = 0; i < 4; i++) bi[i] = *(const f32x4*)&b_in[m0 + i * 16 + quad * 4];
  float bv[4][2][4];
  float ssq0 = 0.f, ssq1 = 0.f;
#pragma unroll
  for (int i = 0; i < 4; i++)
#pragma unroll
    for (int rr = 0; rr < 4; rr++) {
      float v0 = acc[i][0][rr] + bi[i][rr];
      float v1 = acc[i][1][rr] + bi[i][rr];
      bv[i][0][rr] = v0;
      bv[i][1][rr] = v1;
      ssq0 += v0 * v0;
      ssq1 += v1 * v1;
    }
  float inv0 = 1.f, inv1 = 1.f;
  if (seg < 2) {
    float sc = (seg == 0) ? __expf(fminf(ss[h], LOGSMAX)) * LOG2E : 1.f;
    ssq0 += __shfl_xor(ssq0, 16);
    ssq0 += __shfl_xor(ssq0, 32);
    ssq1 += __shfl_xor(ssq1, 16);
    ssq1 += __shfl_xor(ssq1, 32);
    inv0 = sc / fmaxf(sqrtf(ssq0), 1e-12f);
    inv1 = sc / fmaxf(sqrtf(ssq1), 1e-12f);
  }
  unsigned short* dst = (seg == 0 ? qn : (seg == 1 ? kn : vv)) + (size_t)bh * S_ * DH_;
#pragma unroll
  for (int i = 0; i < 4; i++)
#pragma unroll
    for (int j = 0; j < 2; j++) {
      float iv = j ? inv1 : inv0;
      us4 o = {f2bf(bv[i][j][0] * iv), f2bf(bv[i][j][1] * iv),
               f2bf(bv[i][j][2] * iv), f2bf(bv[i][j][3] * iv)};
      int p = n0 + wv * 32 + j * 16 + r15;
      *(us4*)&dst[(size_t)p * DH_ + i * 16 + quad * 4] = o;
    }
}

// ---------------- K5: plain GEMM  C[b][m][n] = sum_k A[m][k] * BT[b][n][k] (fp32 out) ----------------
__global__ __launch_bounds__(256) void k_gemm(const unsigned short* __restrict__ A,
                                              const unsigned short* __restrict__ BT,
                                              float* __restrict__ outp,
                                              int M, int N, int K) {
  __shared__ __align__(16) unsigned short As[64][72];
  __shared__ __align__(16) unsigned short Bs[128][72];
  int t = threadIdx.x;
  int lane = t & 63, wv = t >> 6;
  int quad = lane >> 4, r15 = lane & 15;
  int m0 = blockIdx.y * 64, n0 = blockIdx.x * 128;
  int b = blockIdx.z;
  const unsigned short* BTb = BT + (size_t)b * N * K;

  f32x4 acc[4][2] = {};

  int srA = t >> 2, scA = (t & 3) * 16;
  int srB = t >> 1, scB = (t & 1) * 32;
  const unsigned short* ag = A + (size_t)(m0 + srA) * K + scA;
  const unsigned short* bg = BTb + (size_t)(n0 + srB) * K + scB;

  for (int k0 = 0; k0 < K; k0 += 64) {
    short8 a0 = *(const short8*)(ag + k0);
    short8 a1 = *(const short8*)(ag + k0 + 8);
    short8 b0 = *(const short8*)(bg + k0);
    short8 b1 = *(const short8*)(bg + k0 + 8);
    short8 b2 = *(const short8*)(bg + k0 + 16);
    short8 b3 = *(const short8*)(bg + k0 + 24);
    __syncthreads();
    *(short8*)&As[srA][scA] = a0;
    *(short8*)&As[srA][scA + 8] = a1;
    *(short8*)&Bs[srB][scB] = b0;
    *(short8*)&Bs[srB][scB + 8] = b1;
    *(short8*)&Bs[srB][scB + 16] = b2;
    *(short8*)&Bs[srB][scB + 24] = b3;
    __syncthreads();
#pragma unroll
    for (int ks = 0; ks < 2; ks++) {
      short8 af[4], bfr[2];
#pragma unroll
      for (int i = 0; i < 4; i++) af[i] = *(const short8*)&As[i * 16 + r15][ks * 32 + quad * 8];
#pragma unroll
      for (int j = 0; j < 2; j++) bfr[j] = *(const short8*)&Bs[wv * 32 + j * 16 + r15][ks * 32 + quad * 8];
#pragma unroll
      for (int i = 0; i < 4; i++)
#pragma unroll
        for (int j = 0; j < 2; j++)
          acc[i][j] = __builtin_amdgcn_mfma_f32_16x16x32_bf16(as_bf(af[i]), as_bf(bfr[j]), acc[i][j], 0, 0, 0);
    }
  }
  float* Cb = outp + (size_t)b * M * N;
#pragma unroll
  for (int i = 0; i < 4; i++)
#pragma unroll
    for (int j = 0; j < 2; j++)
#pragma unroll
      for (int rr = 0; rr < 4; rr++) {
        int row = m0 + i * 16 + quad * 4 + rr;
        int col = n0 + wv * 32 + j * 16 + r15;
        Cb[(size_t)row * N + col] = acc[i][j][rr];
      }
}

// ---------------- K3: attention, 32x32 MFMA, 4 waves x 32q, LDS K/V shared, split-K x3 ----------------
// K staged straight; V transposed during staging (dword gather + v_perm repack + b128 writes).
// Fixed-shift softmax; half-up bf16 P pack via v_perm. UNNORMALIZED partial O (bf16) + l (fp32).
__global__ __launch_bounds__(256) void k_attn(const unsigned short* __restrict__ qn,
                                              const unsigned short* __restrict__ kn,
                                              const unsigned short* __restrict__ vv,
                                              const float* __restrict__ ss,
                                              unsigned short* __restrict__ attnp,
                                              float* __restrict__ lp) {
  __shared__ __align__(16) unsigned short Ks[64][72];      // [key][d]
  __shared__ __align__(16) unsigned short Vs[64][72];      // [d][key]
  __shared__ __align__(16) unsigned short Ps[4][32][76];   // per wave [q][key]
  int t = threadIdx.x;
  int w = t >> 6;
  int lane = t & 63;
  int l31 = lane & 31, hi = lane >> 5;
  int bh = blockIdx.x;
  int q0 = blockIdx.y * 128 + w * 32;
  int split = blockIdx.z;
  int ktbase = split * 12;
  const unsigned short* qb = qn + (size_t)bh * S_ * DH_;
  const unsigned short* kb = kn + (size_t)bh * S_ * DH_;
  const unsigned short* vb = vv + (size_t)bh * S_ * DH_;
  float shift2 = __expf(fminf(ss[bh & 7], LOGSMAX)) * LOG2E;  // |s'| <= shift2

  // Q as B-fragment: n=query=l31, k(d) = ks*16 + hi*8 + j
  const unsigned short* qrow = qb + (size_t)(q0 + l31) * DH_ + hi * 8;
  short8 qf[4];
#pragma unroll
  for (int ks = 0; ks < 4; ks++) qf[ks] = *(const short8*)(qrow + ks * 16);

  const f32x16 z16 = {};
  f32x16 O0 = z16, O1 = z16;
  float l_part = 0.f;

  // K staging: 256 threads cover 64x64 K tile, 16 shorts each
  int srow = t >> 2;          // 0..63 (key)
  int scol = (t & 3) * 16;    // d
  const unsigned short* kg = kb + ((size_t)(ktbase * 64) + srow) * DH_ + scol;

  // V transpose staging: thread -> d-pair dp (0..31), key-octet koct (0..7)
  int dp = w * 8 + ((t & 63) >> 3);
  int koct = t & 7;
  const unsigned* vg32 = (const unsigned*)vb + ((size_t)(ktbase * 64 + koct * 8)) * 32 + dp;

  // preload first tile into regs
  short8 kr0 = *(const short8*)(kg);
  short8 kr1 = *(const short8*)(kg + 8);
  unsigned lv[8];
#pragma unroll
  for (int kk = 0; kk < 8; kk++) lv[kk] = vg32[(size_t)kk * 32];

  for (int i = 0; i < 12; i++) {
    __syncthreads();
    *(short8*)&Ks[srow][scol] = kr0;
    *(short8*)&Ks[srow][scol + 8] = kr1;
    {
      u32x4 ev = {pack_lo16(lv[1], lv[0]), pack_lo16(lv[3], lv[2]),
                  pack_lo16(lv[5], lv[4]), pack_lo16(lv[7], lv[6])};
      u32x4 od = {pack_hi16(lv[1], lv[0]), pack_hi16(lv[3], lv[2]),
                  pack_hi16(lv[5], lv[4]), pack_hi16(lv[7], lv[6])};
      *(u32x4*)&Vs[2 * dp][koct * 8] = ev;
      *(u32x4*)&Vs[2 * dp + 1][koct * 8] = od;
    }
    __syncthreads();
    if (i < 11) {  // prefetch next tile; latency hides under compute below
      size_t koff = (size_t)(i + 1) * 64 * DH_;
      kr0 = *(const short8*)(kg + koff);
      kr1 = *(const short8*)(kg + koff + 8);
      const unsigned* vg = vg32 + (size_t)(i + 1) * 64 * 32;
#pragma unroll
      for (int kk = 0; kk < 8; kk++) lv[kk] = vg[(size_t)kk * 32];
    }
    // S^T = K Q^T : A = K-tile (m=key), B = Q regs (n=query)
    f32x16 sc0, sc1;
    {
      short8 a0 = *(const short8*)&Ks[l31][hi * 8];
      short8 a1 = *(const short8*)&Ks[32 + l31][hi * 8];
      sc0 = __builtin_amdgcn_mfma_f32_32x32x16_bf16(as_bf(a0), as_bf(qf[0]), z16, 0, 0, 0);
      sc1 = __builtin_amdgcn_mfma_f32_32x32x16_bf16(as_bf(a1), as_bf(qf[0]), z16, 0, 0, 0);
    }
#pragma unroll
    for (int ks = 1; ks < 4; ks++) {
      short8 a0 = *(const short8*)&Ks[l31][ks * 16 + hi * 8];
      short8 a1 = *(const short8*)&Ks[32 + l31][ks * 16 + hi * 8];
      sc0 = __builtin_amdgcn_mfma_f32_32x32x16_bf16(as_bf(a0), as_bf(qf[ks]), sc0, 0, 0, 0);
      sc1 = __builtin_amdgcn_mfma_f32_32x32x16_bf16(as_bf(a1), as_bf(qf[ks]), sc1, 0, 0, 0);
    }
    // exp2 numerator; half-up bf16 pack (1 v_add + half a v_perm per value); P^T -> per-wave LDS
    float lsum = 0.f;
#pragma unroll
    for (int mt = 0; mt < 2; mt++) {
      const f32x16& s = mt ? sc1 : sc0;
#pragma unroll
      for (int g = 0; g < 4; g++) {
        float e0 = fexp2(s[g * 4 + 0] - shift2);
        float e1 = fexp2(s[g * 4 + 1] - shift2);
        float e2 = fexp2(s[g * 4 + 2] - shift2);
        float e3 = fexp2(s[g * 4 + 3] - shift2);
        lsum += (e0 + e1) + (e2 + e3);
        unsigned u0 = __builtin_bit_cast(unsigned, e0) + 0x8000u;
        unsigned u1 = __builtin_bit_cast(unsigned, e1) + 0x8000u;
        unsigned u2 = __builtin_bit_cast(unsigned, e2) + 0x8000u;
        unsigned u3 = __builtin_bit_cast(unsigned, e3) + 0x8000u;
        u32x2 pk = {pack_hi16(u1, u0), pack_hi16(u3, u2)};
        *(u32x2*)&Ps[w][l31][mt * 32 + g * 8 + hi * 4] = pk;
      }
    }
    l_part += lsum;
    // O^T += V^T P^T : A = V-tile (m=d), B = P (n=query) — same-wave LDS, no barrier
#pragma unroll
    for (int ks = 0; ks < 4; ks++) {
      short8 pb = *(const short8*)&Ps[w][l31][ks * 16 + hi * 8];
      short8 va0 = *(const short8*)&Vs[l31][ks * 16 + hi * 8];
      short8 va1 = *(const short8*)&Vs[32 + l31][ks * 16 + hi * 8];
      O0 = __builtin_amdgcn_mfma_f32_32x32x16_bf16(as_bf(va0), as_bf(pb), O0, 0, 0, 0);
      O1 = __builtin_amdgcn_mfma_f32_32x32x16_bf16(as_bf(va1), as_bf(pb), O1, 0, 0, 0);
    }
  }
  float l = l_part + __shfl_xor(l_part, 32);
  if (hi == 0) lp[((size_t)(split * 16 + bh)) * S_ + q0 + l31] = l;
  unsigned short* orow = attnp + (((size_t)(split * 16 + bh)) * S_ + q0 + l31) * DH_;
#pragma unroll
  for (int mt = 0; mt < 2; mt++) {
    const f32x16& O = mt ? O1 : O0;
#pragma unroll
    for (int g = 0; g < 4; g++) {
      us4 o4 = {f2bf(O[g * 4 + 0]), f2bf(O[g * 4 + 1]), f2bf(O[g * 4 + 2]), f2bf(O[g * 4 + 3])};
      *(us4*)&orow[mt * 32 + g * 8 + hi * 4] = o4;
    }
  }
}

// ---------------- K4: depthwise 3x3 with 3-way split-combine + normalize ----------------
__global__ __launch_bounds__(256) void k_dwconv(const unsigned short* __restrict__ attnp,
                                                const float* __restrict__ lp,
                                                const float* __restrict__ w_dw,
                                                unsigned short* __restrict__ dwb) {
  int t = threadIdx.x;
  int d = t & 63;
  int pj = t >> 6;
  int p = blockIdx.x * 4 + pj;
  int bh = blockIdx.y;
  int b = bh >> 3, h = bh & 7;
  int yy = p / 48, xx = p % 48;
  const unsigned short* a0 = attnp + (size_t)bh * S_ * DH_ + d;
  const unsigned short* a1 = attnp + ((size_t)(16 + bh)) * S_ * DH_ + d;
  const unsigned short* a2 = attnp + ((size_t)(32 + bh)) * S_ * DH_ + d;
  const float* l0 = lp + (size_t)bh * S_;
  const float* l1 = lp + (size_t)(16 + bh) * S_;
  const float* l2 = lp + (size_t)(32 + bh) * S_;
  int ch = h * 64 + d;
  float w[9];
#pragma unroll
  for (int i = 0; i < 9; i++) w[i] = w_dw[ch * 9 + i];
  float acc = 0.f;
#pragma unroll
  for (int dy = -1; dy <= 1; dy++) {
    int y2 = yy + dy;
    if (y2 < 0 || y2 >= 48) continue;
#pragma unroll
    for (int dx = -1; dx <= 1; dx++) {
      int x2 = xx + dx;
      if (x2 < 0 || x2 >= 48) continue;
      int p2 = y2 * 48 + x2;  // wave-uniform
      float rl = frcp(l0[p2] + l1[p2] + l2[p2]);
      float v = (bf2f(a0[(size_t)p2 * DH_]) + bf2f(a1[(size_t)p2 * DH_]) + bf2f(a2[(size_t)p2 * DH_])) * rl;
      acc += v * w[(dy + 1) * 3 + dx + 1];
    }
  }
  dwb[((size_t)b * S_ + p) * INNER_ + ch] = f2bf(acc);
}

// ---------------- K6: channel LN + scales/shifts + final (8-pos chunks) ----------------
__global__ __launch_bounds__(256) void k_ln_final(const float* __restrict__ pw,
                                                  const float* __restrict__ gamma,
                                                  const float* __restrict__ beta,
                                                  const float* __restrict__ x,
                                                  float* __restrict__ out) {
  __shared__ float s_sum[32][9];
  __shared__ float s_ss[32][9];
  int t = threadIdx.x;
  int pl = t & 7, cq = t >> 3;   // 8 positions x 32 channel-groups
  int gid = blockIdx.x;
  int b = gid / (S_ / 8);
  int p = (gid % (S_ / 8)) * 8 + pl;
  const float* pwb = pw + (size_t)b * INNER_ * S_;
  float sum = 0.f, sq = 0.f;
#pragma unroll
  for (int j = 0; j < 16; j++) {
    float v = pwb[(size_t)(cq * 16 + j) * S_ + p];
    sum += v;
    sq += v * v;
  }
  s_sum[cq][pl] = sum;
  s_ss[cq][pl] = sq;
  __syncthreads();
  float tot = 0.f, tss = 0.f;
#pragma unroll
  for (int i = 0; i < 32; i++) {
    tot += s_sum[i][pl];
    tss += s_ss[i][pl];
  }
  float mu = tot * (1.f / 512.f);
  float var = tss * (1.f / 512.f) - mu * mu;
  float rsig = rsqrtf(var + 1e-5f);
  const float* xb = x + (size_t)b * C_ * S_;
  float* ob = out + (size_t)b * C_ * S_;
#pragma unroll
  for (int j = 0; j < 8; j++) {
    int cc = cq * 8 + j;
    float scv = (pwb[(size_t)cc * S_ + p] - mu) * rsig * gamma[cc] + beta[cc];
    float shv = (pwb[(size_t)(cc + 256) * S_ + p] - mu) * rsig * gamma[cc + 256] + beta[cc + 256];
    ob[(size_t)cc * S_ + p] = shv + xb[(size_t)cc * S_ + p] * scv;
  }
}

extern "C" void kernel_launch(void* const* d_in, const int* in_sizes, int n_in,
                              void* d_out, int out_size, void* d_ws, size_t ws_size,
                              hipStream_t stream) {
  const float* x = (const float*)d_in[0];
  const float* w_in = (const float*)d_in[1];
  const float* b_in = (const float*)d_in[2];
  const float* ss = (const float*)d_in[3];
  const float* w_dw = (const float*)d_in[4];
  const float* w_pw = (const float*)d_in[5];
  const float* gamma = (const float*)d_in[6];
  const float* beta = (const float*)d_in[7];
  float* out = (float*)d_out;
  char* ws = (char*)d_ws;

  unsigned short* xT = (unsigned short*)(ws + 0);           // 2,359,296
  unsigned short* w_inb = (unsigned short*)(ws + 2359296);  // 786,432
  unsigned short* w_pwb = (unsigned short*)(ws + 3145728);  // 524,288
  unsigned short* qn = (unsigned short*)(ws + 3670016);     // 4,718,592
  unsigned short* kn = (unsigned short*)(ws + 8388608);     // 4,718,592
  unsigned short* vv = (unsigned short*)(ws + 13107200);    // 4,718,592  [bh][p][d]
  unsigned short* dwb = (unsigned short*)(ws + 17825792);   // 4,718,592
  float* lp = (float*)(ws + 22544384);                      // 442,368  [3][16][2304] fp32
  unsigned short* attnp = (unsigned short*)(ws + 22986752); // bf16 [3][16][2304][64] = 14,155,776
  float* pw = (float*)(ws + 37142528);                      // fp32 [2][512][2304] = 9,437,184

  k_prep<<<2848, 256, 0, stream>>>(x, w_in, w_pw, xT, w_inb, w_pwb);
  k_gemm_qkv<<<dim3(18, 24, 2), 256, 0, stream>>>(w_inb, xT, b_in, ss, qn, kn, vv);
  k_attn<<<dim3(16, 18, 3), 256, 0, stream>>>(qn, kn, vv, ss, attnp, lp);
  k_dwconv<<<dim3(576, 16), 256, 0, stream>>>(attnp, lp, w_dw, dwb);
  k_gemm<<<dim3(18, 8, 2), 256, 0, stream>>>(w_pwb, dwb, pw, INNER_, S_, INNER_);
  k_ln_final<<<576, 256, 0, stream>>>(pw, gamma, beta, x, out);
}

// Round 8
// 173.984 us; speedup vs baseline: 1.2657x; 1.0473x over previous
//
#include <hip/hip_runtime.h>

#define B_ 2
#define C_ 256
#define S_ 2304
#define DH_ 64
#define O3_ 1536
#define INNER_ 512
#define LOGSMAX 4.605170185988092f
#define LOG2E 1.4426950408889634f

typedef __attribute__((ext_vector_type(8))) short short8;
typedef __attribute__((ext_vector_type(4))) float f32x4;
typedef __attribute__((ext_vector_type(16))) float f32x16;
typedef __attribute__((ext_vector_type(4))) unsigned short us4;
typedef __attribute__((ext_vector_type(2))) unsigned u32x2;
typedef __attribute__((ext_vector_type(4))) unsigned u32x4;
typedef __bf16 bf16x8 __attribute__((ext_vector_type(8)));

__device__ __forceinline__ unsigned short f2bf(float f) {
  unsigned u = __builtin_bit_cast(unsigned, f);
  u += 0x7FFFu + ((u >> 16) & 1u);
  return (unsigned short)(u >> 16);
}
__device__ __forceinline__ float bf2f(unsigned short h) {
  return __builtin_bit_cast(float, (unsigned)h << 16);
}
__device__ __forceinline__ bf16x8 as_bf(short8 v) {
  return __builtin_bit_cast(bf16x8, v);
}
__device__ __forceinline__ float fexp2(float x) {
#if __has_builtin(__builtin_amdgcn_exp2f)
  return __builtin_amdgcn_exp2f(x);
#else
  return __expf(x * 0.6931471805599453f);
#endif
}
__device__ __forceinline__ float frcp(float x) {
#if __has_builtin(__builtin_amdgcn_rcpf)
  return __builtin_amdgcn_rcpf(x);
#else
  return 1.f / x;
#endif
}
// pack hi16 of two fp32 bit-patterns: (hi16(b)<<16)|hi16(a) — 1 v_perm_b32
__device__ __forceinline__ unsigned pack_hi16(unsigned b, unsigned a) {
  return __builtin_amdgcn_perm(b, a, 0x07060302u);
}
// pack lo16: (lo16(b)<<16)|lo16(a)
__device__ __forceinline__ unsigned pack_lo16(unsigned b, unsigned a) {
  return __builtin_amdgcn_perm(b, a, 0x05040100u);
}

// ---------------- K0: fused prep: x transpose + both weight converts ----------------
__global__ __launch_bounds__(256) void k_prep(const float* __restrict__ x,
                                              const float* __restrict__ w_in,
                                              const float* __restrict__ w_pw,
                                              unsigned short* __restrict__ xT,
                                              unsigned short* __restrict__ w_inb,
                                              unsigned short* __restrict__ w_pwb) {
  __shared__ float tile[64][65];
  int blk = blockIdx.x;
  int t = threadIdx.x;
  if (blk < 288) {  // transpose x [b][c][p] -> xT [b][p][c] bf16
    int p0 = (blk % 36) * 64, c0 = ((blk / 36) % 4) * 64, b = blk / 144;
    const float* xb = x + (size_t)b * C_ * S_;
#pragma unroll
    for (int i = 0; i < 16; i++) {
      int c = i * 4 + (t >> 6);
      int p = t & 63;
      tile[c][p] = xb[(size_t)(c0 + c) * S_ + p0 + p];
    }
    __syncthreads();
    unsigned short* xTb = xT + (size_t)b * S_ * C_;
#pragma unroll
    for (int i = 0; i < 16; i++) {
      int p = i * 4 + (t >> 6);
      int c = t & 63;
      xTb[(size_t)(p0 + p) * C_ + c0 + c] = f2bf(tile[c][p]);
    }
  } else if (blk < 288 + 1536) {
    int i = (blk - 288) * 256 + t;
    w_inb[i] = f2bf(w_in[i]);
  } else {
    int i = (blk - 1824) * 256 + t;
    w_pwb[i] = f2bf(w_pw[i]);
  }
}

// ---------------- K1: proj_in GEMM with fused bias + l2norm + scale epilogue ----------------
// 64x128 tile; M-tile 64 == one (head, q/k/v-seg) channel group. Writes qn/kn/vv [bh][p][64].
__global__ __launch_bounds__(256) void k_gemm_qkv(const unsigned short* __restrict__ A,
                                                  const unsigned short* __restrict__ BT,
                                                  const float* __restrict__ b_in,
                                                  const float* __restrict__ ss,
                                                  unsigned short* __restrict__ qn,
                                                  unsigned short* __restrict__ kn,
                                                  unsigned short* __restrict__ vv) {
  __shared__ __align__(16) unsigned short As[64][72];
  __shared__ __align__(16) unsigned short Bs[128][72];
  int t = threadIdx.x;
  int lane = t & 63, wv = t >> 6;
  int quad = lane >> 4, r15 = lane & 15;
  int by = blockIdx.y;
  int m0 = by * 64, n0 = blockIdx.x * 128;
  int b = blockIdx.z;
  const unsigned short* BTb = BT + (size_t)b * S_ * C_;

  f32x4 acc[4][2] = {};

  int srA = t >> 2, scA = (t & 3) * 16;
  int srB = t >> 1, scB = (t & 1) * 32;
  const unsigned short* ag = A + (size_t)(m0 + srA) * C_ + scA;
  const unsigned short* bg = BTb + (size_t)(n0 + srB) * C_ + scB;

  for (int k0 = 0; k0 < C_; k0 += 64) {
    short8 a0 = *(const short8*)(ag + k0);
    short8 a1 = *(const short8*)(ag + k0 + 8);
    short8 b0 = *(const short8*)(bg + k0);
    short8 b1 = *(const short8*)(bg + k0 + 8);
    short8 b2 = *(const short8*)(bg + k0 + 16);
    short8 b3 = *(const short8*)(bg + k0 + 24);
    __syncthreads();
    *(short8*)&As[srA][scA] = a0;
    *(short8*)&As[srA][scA + 8] = a1;
    *(short8*)&Bs[srB][scB] = b0;
    *(short8*)&Bs[srB][scB + 8] = b1;
    *(short8*)&Bs[srB][scB + 16] = b2;
    *(short8*)&Bs[srB][scB + 24] = b3;
    __syncthreads();
#pragma unroll
    for (int ks = 0; ks < 2; ks++) {
      short8 af[4], bfr[2];
#pragma unroll
      for (int i = 0; i < 4; i++) af[i] = *(const short8*)&As[i * 16 + r15][ks * 32 + quad * 8];
#pragma unroll
      for (int j = 0; j < 2; j++) bfr[j] = *(const short8*)&Bs[wv * 32 + j * 16 + r15][ks * 32 + quad * 8];
#pragma unroll
      for (int i = 0; i < 4; i++)
#pragma unroll
        for (int j = 0; j < 2; j++)
          acc[i][j] = __builtin_amdgcn_mfma_f32_16x16x32_bf16(as_bf(af[i]), as_bf(bfr[j]), acc[i][j], 0, 0, 0);
    }
  }

  // epilogue: bias add, per-position l2norm (q/k), scale (q), store bf16
  int h = by / 3, seg = by - h * 3;
  int bh = b * 8 + h;
  f32x4 bi[4];
#pragma unroll
  for (int i = 0; i < 4; i++) bi[i] = *(const f32x4*)&b_in[m0 + i * 16 + quad * 4];
  float bv[4][2][4];
  float ssq0 = 0.f, ssq1 = 0.f;
#pragma unroll
  for (int i = 0; i < 4; i++)
#pragma unroll
    for (int rr = 0; rr < 4; rr++) {
      float v0 = acc[i][0][rr] + bi[i][rr];
      float v1 = acc[i][1][rr] + bi[i][rr];
      bv[i][0][rr] = v0;
      bv[i][1][rr] = v1;
      ssq0 += v0 * v0;
      ssq1 += v1 * v1;
    }
  float inv0 = 1.f, inv1 = 1.f;
  if (seg < 2) {
    float sc = (seg == 0) ? __expf(fminf(ss[h], LOGSMAX)) * LOG2E : 1.f;
    ssq0 += __shfl_xor(ssq0, 16);
    ssq0 += __shfl_xor(ssq0, 32);
    ssq1 += __shfl_xor(ssq1, 16);
    ssq1 += __shfl_xor(ssq1, 32);
    inv0 = sc / fmaxf(sqrtf(ssq0), 1e-12f);
    inv1 = sc / fmaxf(sqrtf(ssq1), 1e-12f);
  }
  unsigned short* dst = (seg == 0 ? qn : (seg == 1 ? kn : vv)) + (size_t)bh * S_ * DH_;
#pragma unroll
  for (int i = 0; i < 4; i++)
#pragma unroll
    for (int j = 0; j < 2; j++) {
      float iv = j ? inv1 : inv0;
      us4 o = {f2bf(bv[i][j][0] * iv), f2bf(bv[i][j][1] * iv),
               f2bf(bv[i][j][2] * iv), f2bf(bv[i][j][3] * iv)};
      int p = n0 + wv * 32 + j * 16 + r15;
      *(us4*)&dst[(size_t)p * DH_ + i * 16 + quad * 4] = o;
    }
}

// ---------------- K5: plain GEMM  C[b][m][n] = sum_k A[m][k] * BT[b][n][k] (fp32 out) ----------------
__global__ __launch_bounds__(256) void k_gemm(const unsigned short* __restrict__ A,
                                              const unsigned short* __restrict__ BT,
                                              float* __restrict__ outp,
                                              int M, int N, int K) {
  __shared__ __align__(16) unsigned short As[64][72];
  __shared__ __align__(16) unsigned short Bs[128][72];
  int t = threadIdx.x;
  int lane = t & 63, wv = t >> 6;
  int quad = lane >> 4, r15 = lane & 15;
  int m0 = blockIdx.y * 64, n0 = blockIdx.x * 128;
  int b = blockIdx.z;
  const unsigned short* BTb = BT + (size_t)b * N * K;

  f32x4 acc[4][2] = {};

  int srA = t >> 2, scA = (t & 3) * 16;
  int srB = t >> 1, scB = (t & 1) * 32;
  const unsigned short* ag = A + (size_t)(m0 + srA) * K + scA;
  const unsigned short* bg = BTb + (size_t)(n0 + srB) * K + scB;

  for (int k0 = 0; k0 < K; k0 += 64) {
    short8 a0 = *(const short8*)(ag + k0);
    short8 a1 = *(const short8*)(ag + k0 + 8);
    short8 b0 = *(const short8*)(bg + k0);
    short8 b1 = *(const short8*)(bg + k0 + 8);
    short8 b2 = *(const short8*)(bg + k0 + 16);
    short8 b3 = *(const short8*)(bg + k0 + 24);
    __syncthreads();
    *(short8*)&As[srA][scA] = a0;
    *(short8*)&As[srA][scA + 8] = a1;
    *(short8*)&Bs[srB][scB] = b0;
    *(short8*)&Bs[srB][scB + 8] = b1;
    *(short8*)&Bs[srB][scB + 16] = b2;
    *(short8*)&Bs[srB][scB + 24] = b3;
    __syncthreads();
#pragma unroll
    for (int ks = 0; ks < 2; ks++) {
      short8 af[4], bfr[2];
#pragma unroll
      for (int i = 0; i < 4; i++) af[i] = *(const short8*)&As[i * 16 + r15][ks * 32 + quad * 8];
#pragma unroll
      for (int j = 0; j < 2; j++) bfr[j] = *(const short8*)&Bs[wv * 32 + j * 16 + r15][ks * 32 + quad * 8];
#pragma unroll
      for (int i = 0; i < 4; i++)
#pragma unroll
        for (int j = 0; j < 2; j++)
          acc[i][j] = __builtin_amdgcn_mfma_f32_16x16x32_bf16(as_bf(af[i]), as_bf(bfr[j]), acc[i][j], 0, 0, 0);
    }
  }
  float* Cb = outp + (size_t)b * M * N;
#pragma unroll
  for (int i = 0; i < 4; i++)
#pragma unroll
    for (int j = 0; j < 2; j++)
#pragma unroll
      for (int rr = 0; rr < 4; rr++) {
        int row = m0 + i * 16 + quad * 4 + rr;
        int col = n0 + wv * 32 + j * 16 + r15;
        Cb[(size_t)row * N + col] = acc[i][j][rr];
      }
}

// ---------------- K3: attention, 32x32 MFMA, 4 waves x 32q, LDS K/V shared, split-K x3 ----------------
// Grid (qtile, split, bh): same-bh blocks linearly consecutive -> XCD L2 locality.
__global__ __launch_bounds__(256) void k_attn(const unsigned short* __restrict__ qn,
                                              const unsigned short* __restrict__ kn,
                                              const unsigned short* __restrict__ vv,
                                              const float* __restrict__ ss,
                                              unsigned short* __restrict__ attnp,
                                              float* __restrict__ lp) {
  __shared__ __align__(16) unsigned short Ks[64][72];      // [key][d]
  __shared__ __align__(16) unsigned short Vs[64][72];      // [d][key]
  __shared__ __align__(16) unsigned short Ps[4][32][76];   // per wave [q][key]
  int t = threadIdx.x;
  int w = t >> 6;
  int lane = t & 63;
  int l31 = lane & 31, hi = lane >> 5;
  int bh = blockIdx.z;
  int q0 = blockIdx.x * 128 + w * 32;
  int split = blockIdx.y;
  int ktbase = split * 12;
  const unsigned short* qb = qn + (size_t)bh * S_ * DH_;
  const unsigned short* kb = kn + (size_t)bh * S_ * DH_;
  const unsigned short* vb = vv + (size_t)bh * S_ * DH_;
  float shift2 = __expf(fminf(ss[bh & 7], LOGSMAX)) * LOG2E;  // |s'| <= shift2

  // Q as B-fragment: n=query=l31, k(d) = ks*16 + hi*8 + j
  const unsigned short* qrow = qb + (size_t)(q0 + l31) * DH_ + hi * 8;
  short8 qf[4];
#pragma unroll
  for (int ks = 0; ks < 4; ks++) qf[ks] = *(const short8*)(qrow + ks * 16);

  const f32x16 z16 = {};
  f32x16 O0 = z16, O1 = z16;
  float l_part = 0.f;

  // K staging: 256 threads cover 64x64 K tile, 16 shorts each
  int srow = t >> 2;          // 0..63 (key)
  int scol = (t & 3) * 16;    // d
  const unsigned short* kg = kb + ((size_t)(ktbase * 64) + srow) * DH_ + scol;

  // V transpose staging: thread -> d-pair dp (0..31), key-octet koct (0..7)
  int dp = w * 8 + ((t & 63) >> 3);
  int koct = t & 7;
  const unsigned* vg32 = (const unsigned*)vb + ((size_t)(ktbase * 64 + koct * 8)) * 32 + dp;

  // preload first tile into regs
  short8 kr0 = *(const short8*)(kg);
  short8 kr1 = *(const short8*)(kg + 8);
  unsigned lv[8];
#pragma unroll
  for (int kk = 0; kk < 8; kk++) lv[kk] = vg32[(size_t)kk * 32];

  for (int i = 0; i < 12; i++) {
    __syncthreads();
    *(short8*)&Ks[srow][scol] = kr0;
    *(short8*)&Ks[srow][scol + 8] = kr1;
    {
      u32x4 ev = {pack_lo16(lv[1], lv[0]), pack_lo16(lv[3], lv[2]),
                  pack_lo16(lv[5], lv[4]), pack_lo16(lv[7], lv[6])};
      u32x4 od = {pack_hi16(lv[1], lv[0]), pack_hi16(lv[3], lv[2]),
                  pack_hi16(lv[5], lv[4]), pack_hi16(lv[7], lv[6])};
      *(u32x4*)&Vs[2 * dp][koct * 8] = ev;
      *(u32x4*)&Vs[2 * dp + 1][koct * 8] = od;
    }
    __syncthreads();
    if (i < 11) {  // prefetch next tile; latency hides under compute below
      size_t koff = (size_t)(i + 1) * 64 * DH_;
      kr0 = *(const short8*)(kg + koff);
      kr1 = *(const short8*)(kg + koff + 8);
      const unsigned* vg = vg32 + (size_t)(i + 1) * 64 * 32;
#pragma unroll
      for (int kk = 0; kk < 8; kk++) lv[kk] = vg[(size_t)kk * 32];
    }
    // S^T = K Q^T : A = K-tile (m=key), B = Q regs (n=query)
    f32x16 sc0, sc1;
    {
      short8 a0 = *(const short8*)&Ks[l31][hi * 8];
      short8 a1 = *(const short8*)&Ks[32 + l31][hi * 8];
      sc0 = __builtin_amdgcn_mfma_f32_32x32x16_bf16(as_bf(a0), as_bf(qf[0]), z16, 0, 0, 0);
      sc1 = __builtin_amdgcn_mfma_f32_32x32x16_bf16(as_bf(a1), as_bf(qf[0]), z16, 0, 0, 0);
    }
#pragma unroll
    for (int ks = 1; ks < 4; ks++) {
      short8 a0 = *(const short8*)&Ks[l31][ks * 16 + hi * 8];
      short8 a1 = *(const short8*)&Ks[32 + l31][ks * 16 + hi * 8];
      sc0 = __builtin_amdgcn_mfma_f32_32x32x16_bf16(as_bf(a0), as_bf(qf[ks]), sc0, 0, 0, 0);
      sc1 = __builtin_amdgcn_mfma_f32_32x32x16_bf16(as_bf(a1), as_bf(qf[ks]), sc1, 0, 0, 0);
    }
    // exp2 numerator; half-up bf16 pack; P^T -> per-wave LDS
    float lsum = 0.f;
#pragma unroll
    for (int mt = 0; mt < 2; mt++) {
      const f32x16& s = mt ? sc1 : sc0;
#pragma unroll
      for (int g = 0; g < 4; g++) {
        float e0 = fexp2(s[g * 4 + 0] - shift2);
        float e1 = fexp2(s[g * 4 + 1] - shift2);
        float e2 = fexp2(s[g * 4 + 2] - shift2);
        float e3 = fexp2(s[g * 4 + 3] - shift2);
        lsum += (e0 + e1) + (e2 + e3);
        unsigned u0 = __builtin_bit_cast(unsigned, e0) + 0x8000u;
        unsigned u1 = __builtin_bit_cast(unsigned, e1) + 0x8000u;
        unsigned u2 = __builtin_bit_cast(unsigned, e2) + 0x8000u;
        unsigned u3 = __builtin_bit_cast(unsigned, e3) + 0x8000u;
        u32x2 pk = {pack_hi16(u1, u0), pack_hi16(u3, u2)};
        *(u32x2*)&Ps[w][l31][mt * 32 + g * 8 + hi * 4] = pk;
      }
    }
    l_part += lsum;
    // O^T += V^T P^T : A = V-tile (m=d), B = P (n=query) — same-wave LDS, no barrier
#pragma unroll
    for (int ks = 0; ks < 4; ks++) {
      short8 pb = *(const short8*)&Ps[w][l31][ks * 16 + hi * 8];
      short8 va0 = *(const short8*)&Vs[l31][ks * 16 + hi * 8];
      short8 va1 = *(const short8*)&Vs[32 + l31][ks * 16 + hi * 8];
      O0 = __builtin_amdgcn_mfma_f32_32x32x16_bf16(as_bf(va0), as_bf(pb), O0, 0, 0, 0);
      O1 = __builtin_amdgcn_mfma_f32_32x32x16_bf16(as_bf(va1), as_bf(pb), O1, 0, 0, 0);
    }
  }
  float l = l_part + __shfl_xor(l_part, 32);
  if (hi == 0) lp[((size_t)(split * 16 + bh)) * S_ + q0 + l31] = l;
  unsigned short* orow = attnp + (((size_t)(split * 16 + bh)) * S_ + q0 + l31) * DH_;
#pragma unroll
  for (int mt = 0; mt < 2; mt++) {
    const f32x16& O = mt ? O1 : O0;
#pragma unroll
    for (int g = 0; g < 4; g++) {
      us4 o4 = {f2bf(O[g * 4 + 0]), f2bf(O[g * 4 + 1]), f2bf(O[g * 4 + 2]), f2bf(O[g * 4 + 3])};
      *(us4*)&orow[mt * 32 + g * 8 + hi * 4] = o4;
    }
  }
}

// ---------------- K4: depthwise 3x3 with 3-way split-combine + normalize ----------------
__global__ __launch_bounds__(256) void k_dwconv(const unsigned short* __restrict__ attnp,
                                                const float* __restrict__ lp,
                                                const float* __restrict__ w_dw,
                                                unsigned short* __restrict__ dwb) {
  int t = threadIdx.x;
  int d = t & 63;
  int pj = t >> 6;
  int p = blockIdx.x * 4 + pj;
  int bh = blockIdx.y;
  int b = bh >> 3, h = bh & 7;
  int yy = p / 48, xx = p % 48;
  const unsigned short* a0 = attnp + (size_t)bh * S_ * DH_ + d;
  const unsigned short* a1 = attnp + ((size_t)(16 + bh)) * S_ * DH_ + d;
  const unsigned short* a2 = attnp + ((size_t)(32 + bh)) * S_ * DH_ + d;
  const float* l0 = lp + (size_t)bh * S_;
  const float* l1 = lp + (size_t)(16 + bh) * S_;
  const float* l2 = lp + (size_t)(32 + bh) * S_;
  int ch = h * 64 + d;
  float w[9];
#pragma unroll
  for (int i = 0; i < 9; i++) w[i] = w_dw[ch * 9 + i];
  float acc = 0.f;
#pragma unroll
  for (int dy = -1; dy <= 1; dy++) {
    int y2 = yy + dy;
    if (y2 < 0 || y2 >= 48) continue;
#pragma unroll
    for (int dx = -1; dx <= 1; dx++) {
      int x2 = xx + dx;
      if (x2 < 0 || x2 >= 48) continue;
      int p2 = y2 * 48 + x2;  // wave-uniform
      float rl = frcp(l0[p2] + l1[p2] + l2[p2]);
      float v = (bf2f(a0[(size_t)p2 * DH_]) + bf2f(a1[(size_t)p2 * DH_]) + bf2f(a2[(size_t)p2 * DH_])) * rl;
      acc += v * w[(dy + 1) * 3 + dx + 1];
    }
  }
  dwb[((size_t)b * S_ + p) * INNER_ + ch] = f2bf(acc);
}

// ---------------- K6: channel LN + scales/shifts + final ----------------
// 16 positions/block, float2 per thread: 64B coalesced segments. Grid (144, 2).
__global__ __launch_bounds__(256) void k_ln_final(const float* __restrict__ pw,
                                                  const float* __restrict__ gamma,
                                                  const float* __restrict__ beta,
                                                  const float* __restrict__ x,
                                                  float* __restrict__ out) {
  __shared__ float s_s0[32][8], s_s1[32][8], s_q0[32][8], s_q1[32][8];
  int t = threadIdx.x;
  int pl = t & 7, g = t >> 3;               // 8 position-pairs x 32 channel-groups
  int b = blockIdx.y;
  int p = blockIdx.x * 16 + pl * 2;
  const float* pwb = pw + (size_t)b * INNER_ * S_ + p;
  float s0 = 0.f, s1 = 0.f, q0 = 0.f, q1 = 0.f;
#pragma unroll
  for (int j = 0; j < 16; j++) {
    float2 v = *(const float2*)&pwb[(size_t)(g * 16 + j) * S_];
    s0 += v.x; s1 += v.y;
    q0 += v.x * v.x; q1 += v.y * v.y;
  }
  s_s0[g][pl] = s0; s_s1[g][pl] = s1;
  s_q0[g][pl] = q0; s_q1[g][pl] = q1;
  __syncthreads();
  float t0 = 0.f, t1 = 0.f, u0 = 0.f, u1 = 0.f;
#pragma unroll
  for (int i = 0; i < 32; i++) {
    t0 += s_s0[i][pl]; t1 += s_s1[i][pl];
    u0 += s_q0[i][pl]; u1 += s_q1[i][pl];
  }
  float mu0 = t0 * (1.f / 512.f), mu1 = t1 * (1.f / 512.f);
  float rs0 = rsqrtf(u0 * (1.f / 512.f) - mu0 * mu0 + 1e-5f);
  float rs1 = rsqrtf(u1 * (1.f / 512.f) - mu1 * mu1 + 1e-5f);
  const float* xb = x + (size_t)b * C_ * S_ + p;
  float* ob = out + (size_t)b * C_ * S_ + p;
#pragma unroll
  for (int j = 0; j < 8; j++) {
    int cc = g * 8 + j;  // 0..255
    float ga = gamma[cc], be = beta[cc];
    float gs = gamma[cc + 256], bs = beta[cc + 256];
    float2 pv = *(const float2*)&pwb[(size_t)cc * S_];
    float2 sv = *(const float2*)&pwb[(size_t)(cc + 256) * S_];
    float2 xv = *(const float2*)&xb[(size_t)cc * S_];
    float sc0 = (pv.x - mu0) * rs0 * ga + be;
    float sc1 = (pv.y - mu1) * rs1 * ga + be;
    float sh0 = (sv.x - mu0) * rs0 * gs + bs;
    float sh1 = (sv.y - mu1) * rs1 * gs + bs;
    float2 o;
    o.x = sh0 + xv.x * sc0;
    o.y = sh1 + xv.y * sc1;
    *(float2*)&ob[(size_t)cc * S_] = o;
  }
}

extern "C" void kernel_launch(void* const* d_in, const int* in_sizes, int n_in,
                              void* d_out, int out_size, void* d_ws, size_t ws_size,
                              hipStream_t stream) {
  const float* x = (const float*)d_in[0];
  const float* w_in = (const float*)d_in[1];
  const float* b_in = (const float*)d_in[2];
  const float* ss = (const float*)d_in[3];
  const float* w_dw = (const float*)d_in[4];
  const float* w_pw = (const float*)d_in[5];
  const float* gamma = (const float*)d_in[6];
  const float* beta = (const float*)d_in[7];
  float* out = (float*)d_out;
  char* ws = (char*)d_ws;

  unsigned short* xT = (unsigned short*)(ws + 0);           // 2,359,296
  unsigned short* w_inb = (unsigned short*)(ws + 2359296);  // 786,432
  unsigned short* w_pwb = (unsigned short*)(ws + 3145728);  // 524,288
  unsigned short* qn = (unsigned short*)(ws + 3670016);     // 4,718,592
  unsigned short* kn = (unsigned short*)(ws + 8388608);     // 4,718,592
  unsigned short* vv = (unsigned short*)(ws + 13107200);    // 4,718,592  [bh][p][d]
  unsigned short* dwb = (unsigned short*)(ws + 17825792);   // 4,718,592
  float* lp = (float*)(ws + 22544384);                      // 442,368  [3][16][2304] fp32
  unsigned short* attnp = (unsigned short*)(ws + 22986752); // bf16 [3][16][2304][64] = 14,155,776
  float* pw = (float*)(ws + 37142528);                      // fp32 [2][512][2304] = 9,437,184

  k_prep<<<2848, 256, 0, stream>>>(x, w_in, w_pw, xT, w_inb, w_pwb);
  k_gemm_qkv<<<dim3(18, 24, 2), 256, 0, stream>>>(w_inb, xT, b_in, ss, qn, kn, vv);
  k_attn<<<dim3(18, 3, 16), 256, 0, stream>>>(qn, kn, vv, ss, attnp, lp);
  k_dwconv<<<dim3(576, 16), 256, 0, stream>>>(attnp, lp, w_dw, dwb);
  k_gemm<<<dim3(18, 8, 2), 256, 0, stream>>>(w_pwb, dwb, pw, INNER_, S_, INNER_);
  k_ln_final<<<dim3(144, 2), 256, 0, stream>>>(pw, gamma, beta, x, out);
}

// Round 9
// 171.859 us; speedup vs baseline: 1.2813x; 1.0124x over previous
//
#include <hip/hip_runtime.h>

#define B_ 2
#define C_ 256
#define S_ 2304
#define DH_ 64
#define O3_ 1536
#define INNER_ 512
#define LOGSMAX 4.605170185988092f
#define LOG2E 1.4426950408889634f

typedef __attribute__((ext_vector_type(8))) short short8;
typedef __attribute__((ext_vector_type(4))) float f32x4;
typedef __attribute__((ext_vector_type(16))) float f32x16;
typedef __attribute__((ext_vector_type(4))) unsigned short us4;
typedef __attribute__((ext_vector_type(2))) unsigned u32x2;
typedef __attribute__((ext_vector_type(4))) unsigned u32x4;
typedef __bf16 bf16x8 __attribute__((ext_vector_type(8)));

__device__ __forceinline__ unsigned short f2bf(float f) {
  unsigned u = __builtin_bit_cast(unsigned, f);
  u += 0x7FFFu + ((u >> 16) & 1u);
  return (unsigned short)(u >> 16);
}
__device__ __forceinline__ float bf2f(unsigned short h) {
  return __builtin_bit_cast(float, (unsigned)h << 16);
}
__device__ __forceinline__ bf16x8 as_bf(short8 v) {
  return __builtin_bit_cast(bf16x8, v);
}
__device__ __forceinline__ float fexp2(float x) {
#if __has_builtin(__builtin_amdgcn_exp2f)
  return __builtin_amdgcn_exp2f(x);
#else
  return __expf(x * 0.6931471805599453f);
#endif
}
__device__ __forceinline__ float frcp(float x) {
#if __has_builtin(__builtin_amdgcn_rcpf)
  return __builtin_amdgcn_rcpf(x);
#else
  return 1.f / x;
#endif
}
// pack hi16 of two fp32 bit-patterns: (hi16(b)<<16)|hi16(a) — 1 v_perm_b32
__device__ __forceinline__ unsigned pack_hi16(unsigned b, unsigned a) {
  return __builtin_amdgcn_perm(b, a, 0x07060302u);
}
// pack lo16: (lo16(b)<<16)|lo16(a)
__device__ __forceinline__ unsigned pack_lo16(unsigned b, unsigned a) {
  return __builtin_amdgcn_perm(b, a, 0x05040100u);
}

// ---------------- K0: fused prep: x transpose + both weight converts ----------------
__global__ __launch_bounds__(256) void k_prep(const float* __restrict__ x,
                                              const float* __restrict__ w_in,
                                              const float* __restrict__ w_pw,
                                              unsigned short* __restrict__ xT,
                                              unsigned short* __restrict__ w_inb,
                                              unsigned short* __restrict__ w_pwb) {
  __shared__ float tile[64][65];
  int blk = blockIdx.x;
  int t = threadIdx.x;
  if (blk < 288) {  // transpose x [b][c][p] -> xT [b][p][c] bf16
    int p0 = (blk % 36) * 64, c0 = ((blk / 36) % 4) * 64, b = blk / 144;
    const float* xb = x + (size_t)b * C_ * S_;
#pragma unroll
    for (int i = 0; i < 16; i++) {
      int c = i * 4 + (t >> 6);
      int p = t & 63;
      tile[c][p] = xb[(size_t)(c0 + c) * S_ + p0 + p];
    }
    __syncthreads();
    unsigned short* xTb = xT + (size_t)b * S_ * C_;
#pragma unroll
    for (int i = 0; i < 16; i++) {
      int p = i * 4 + (t >> 6);
      int c = t & 63;
      xTb[(size_t)(p0 + p) * C_ + c0 + c] = f2bf(tile[c][p]);
    }
  } else if (blk < 288 + 1536) {
    int i = (blk - 288) * 256 + t;
    w_inb[i] = f2bf(w_in[i]);
  } else {
    int i = (blk - 1824) * 256 + t;
    w_pwb[i] = f2bf(w_pw[i]);
  }
}

// ---------------- K1: proj_in GEMM with fused bias + l2norm + scale epilogue ----------------
// 64x128 tile; M-tile 64 == one (head, q/k/v-seg) channel group. Writes qn/kn/vv [bh][p][64].
__global__ __launch_bounds__(256) void k_gemm_qkv(const unsigned short* __restrict__ A,
                                                  const unsigned short* __restrict__ BT,
                                                  const float* __restrict__ b_in,
                                                  const float* __restrict__ ss,
                                                  unsigned short* __restrict__ qn,
                                                  unsigned short* __restrict__ kn,
                                                  unsigned short* __restrict__ vv) {
  __shared__ __align__(16) unsigned short As[64][72];
  __shared__ __align__(16) unsigned short Bs[128][72];
  int t = threadIdx.x;
  int lane = t & 63, wv = t >> 6;
  int quad = lane >> 4, r15 = lane & 15;
  int by = blockIdx.y;
  int m0 = by * 64, n0 = blockIdx.x * 128;
  int b = blockIdx.z;
  const unsigned short* BTb = BT + (size_t)b * S_ * C_;

  f32x4 acc[4][2] = {};

  int srA = t >> 2, scA = (t & 3) * 16;
  int srB = t >> 1, scB = (t & 1) * 32;
  const unsigned short* ag = A + (size_t)(m0 + srA) * C_ + scA;
  const unsigned short* bg = BTb + (size_t)(n0 + srB) * C_ + scB;

  for (int k0 = 0; k0 < C_; k0 += 64) {
    short8 a0 = *(const short8*)(ag + k0);
    short8 a1 = *(const short8*)(ag + k0 + 8);
    short8 b0 = *(const short8*)(bg + k0);
    short8 b1 = *(const short8*)(bg + k0 + 8);
    short8 b2 = *(const short8*)(bg + k0 + 16);
    short8 b3 = *(const short8*)(bg + k0 + 24);
    __syncthreads();
    *(short8*)&As[srA][scA] = a0;
    *(short8*)&As[srA][scA + 8] = a1;
    *(short8*)&Bs[srB][scB] = b0;
    *(short8*)&Bs[srB][scB + 8] = b1;
    *(short8*)&Bs[srB][scB + 16] = b2;
    *(short8*)&Bs[srB][scB + 24] = b3;
    __syncthreads();
#pragma unroll
    for (int ks = 0; ks < 2; ks++) {
      short8 af[4], bfr[2];
#pragma unroll
      for (int i = 0; i < 4; i++) af[i] = *(const short8*)&As[i * 16 + r15][ks * 32 + quad * 8];
#pragma unroll
      for (int j = 0; j < 2; j++) bfr[j] = *(const short8*)&Bs[wv * 32 + j * 16 + r15][ks * 32 + quad * 8];
#pragma unroll
      for (int i = 0; i < 4; i++)
#pragma unroll
        for (int j = 0; j < 2; j++)
          acc[i][j] = __builtin_amdgcn_mfma_f32_16x16x32_bf16(as_bf(af[i]), as_bf(bfr[j]), acc[i][j], 0, 0, 0);
    }
  }

  // epilogue: bias add, per-position l2norm (q/k), scale (q), store bf16
  int h = by / 3, seg = by - h * 3;
  int bh = b * 8 + h;
  f32x4 bi[4];
#pragma unroll
  for (int i = 0; i < 4; i++) bi[i] = *(const f32x4*)&b_in[m0 + i * 16 + quad * 4];
  float bv[4][2][4];
  float ssq0 = 0.f, ssq1 = 0.f;
#pragma unroll
  for (int i = 0; i < 4; i++)
#pragma unroll
    for (int rr = 0; rr < 4; rr++) {
      float v0 = acc[i][0][rr] + bi[i][rr];
      float v1 = acc[i][1][rr] + bi[i][rr];
      bv[i][0][rr] = v0;
      bv[i][1][rr] = v1;
      ssq0 += v0 * v0;
      ssq1 += v1 * v1;
    }
  float inv0 = 1.f, inv1 = 1.f;
  if (seg < 2) {
    float sc = (seg == 0) ? __expf(fminf(ss[h], LOGSMAX)) * LOG2E : 1.f;
    ssq0 += __shfl_xor(ssq0, 16);
    ssq0 += __shfl_xor(ssq0, 32);
    ssq1 += __shfl_xor(ssq1, 16);
    ssq1 += __shfl_xor(ssq1, 32);
    inv0 = sc / fmaxf(sqrtf(ssq0), 1e-12f);
    inv1 = sc / fmaxf(sqrtf(ssq1), 1e-12f);
  }
  unsigned short* dst = (seg == 0 ? qn : (seg == 1 ? kn : vv)) + (size_t)bh * S_ * DH_;
#pragma unroll
  for (int i = 0; i < 4; i++)
#pragma unroll
    for (int j = 0; j < 2; j++) {
      float iv = j ? inv1 : inv0;
      us4 o = {f2bf(bv[i][j][0] * iv), f2bf(bv[i][j][1] * iv),
               f2bf(bv[i][j][2] * iv), f2bf(bv[i][j][3] * iv)};
      int p = n0 + wv * 32 + j * 16 + r15;
      *(us4*)&dst[(size_t)p * DH_ + i * 16 + quad * 4] = o;
    }
}

// ---------------- K5: pw GEMM, 64x64 tile, 2 waves, 576 blocks for load balance ----------------
__global__ __launch_bounds__(128) void k_gemm2(const unsigned short* __restrict__ A,
                                               const unsigned short* __restrict__ BT,
                                               float* __restrict__ outp,
                                               int M, int N, int K) {
  __shared__ __align__(16) unsigned short As[64][72];
  __shared__ __align__(16) unsigned short Bs[64][72];
  int t = threadIdx.x;
  int lane = t & 63, wv = t >> 6;
  int quad = lane >> 4, r15 = lane & 15;
  int m0 = blockIdx.y * 64, n0 = blockIdx.x * 64;
  int b = blockIdx.z;
  const unsigned short* BTb = BT + (size_t)b * N * K;

  f32x4 acc[4][2] = {};

  int sr = t >> 1, sc = (t & 1) * 32;
  const unsigned short* ag = A + (size_t)(m0 + sr) * K + sc;
  const unsigned short* bg = BTb + (size_t)(n0 + sr) * K + sc;

  for (int k0 = 0; k0 < K; k0 += 64) {
    short8 a0 = *(const short8*)(ag + k0);
    short8 a1 = *(const short8*)(ag + k0 + 8);
    short8 a2 = *(const short8*)(ag + k0 + 16);
    short8 a3 = *(const short8*)(ag + k0 + 24);
    short8 b0 = *(const short8*)(bg + k0);
    short8 b1 = *(const short8*)(bg + k0 + 8);
    short8 b2 = *(const short8*)(bg + k0 + 16);
    short8 b3 = *(const short8*)(bg + k0 + 24);
    __syncthreads();
    *(short8*)&As[sr][sc] = a0;
    *(short8*)&As[sr][sc + 8] = a1;
    *(short8*)&As[sr][sc + 16] = a2;
    *(short8*)&As[sr][sc + 24] = a3;
    *(short8*)&Bs[sr][sc] = b0;
    *(short8*)&Bs[sr][sc + 8] = b1;
    *(short8*)&Bs[sr][sc + 16] = b2;
    *(short8*)&Bs[sr][sc + 24] = b3;
    __syncthreads();
#pragma unroll
    for (int ks = 0; ks < 2; ks++) {
      short8 af[4], bfr[2];
#pragma unroll
      for (int i = 0; i < 4; i++) af[i] = *(const short8*)&As[i * 16 + r15][ks * 32 + quad * 8];
#pragma unroll
      for (int j = 0; j < 2; j++) bfr[j] = *(const short8*)&Bs[wv * 32 + j * 16 + r15][ks * 32 + quad * 8];
#pragma unroll
      for (int i = 0; i < 4; i++)
#pragma unroll
        for (int j = 0; j < 2; j++)
          acc[i][j] = __builtin_amdgcn_mfma_f32_16x16x32_bf16(as_bf(af[i]), as_bf(bfr[j]), acc[i][j], 0, 0, 0);
    }
  }
  float* Cb = outp + (size_t)b * M * N;
#pragma unroll
  for (int i = 0; i < 4; i++)
#pragma unroll
    for (int j = 0; j < 2; j++)
#pragma unroll
      for (int rr = 0; rr < 4; rr++) {
        int row = m0 + i * 16 + quad * 4 + rr;
        int col = n0 + wv * 32 + j * 16 + r15;
        Cb[(size_t)row * N + col] = acc[i][j][rr];
      }
}

// ---------------- K3: attention, 32x32 MFMA, 4 waves x 32q, LDS K/V shared, split-K x3 ----------------
// Grid (bh, qtile, split): bh fastest -> XCD = bh%8 pinned (round-robin linear id).
__global__ __launch_bounds__(256) void k_attn(const unsigned short* __restrict__ qn,
                                              const unsigned short* __restrict__ kn,
                                              const unsigned short* __restrict__ vv,
                                              const float* __restrict__ ss,
                                              unsigned short* __restrict__ attnp,
                                              float* __restrict__ lp) {
  __shared__ __align__(16) unsigned short Ks[64][72];      // [key][d]
  __shared__ __align__(16) unsigned short Vs[64][72];      // [d][key]
  __shared__ __align__(16) unsigned short Ps[4][32][76];   // per wave [q][key]
  int t = threadIdx.x;
  int w = t >> 6;
  int lane = t & 63;
  int l31 = lane & 31, hi = lane >> 5;
  int bh = blockIdx.x;
  int q0 = blockIdx.y * 128 + w * 32;
  int split = blockIdx.z;
  int ktbase = split * 12;
  const unsigned short* qb = qn + (size_t)bh * S_ * DH_;
  const unsigned short* kb = kn + (size_t)bh * S_ * DH_;
  const unsigned short* vb = vv + (size_t)bh * S_ * DH_;
  float shift2 = __expf(fminf(ss[bh & 7], LOGSMAX)) * LOG2E;  // |s'| <= shift2

  // Q as B-fragment: n=query=l31, k(d) = ks*16 + hi*8 + j
  const unsigned short* qrow = qb + (size_t)(q0 + l31) * DH_ + hi * 8;
  short8 qf[4];
#pragma unroll
  for (int ks = 0; ks < 4; ks++) qf[ks] = *(const short8*)(qrow + ks * 16);

  const f32x16 z16 = {};
  f32x16 O0 = z16, O1 = z16;
  float l_part = 0.f;

  // K staging: 256 threads cover 64x64 K tile, 16 shorts each
  int srow = t >> 2;          // 0..63 (key)
  int scol = (t & 3) * 16;    // d
  const unsigned short* kg = kb + ((size_t)(ktbase * 64) + srow) * DH_ + scol;

  // V transpose staging: thread -> d-pair dp (0..31), key-octet koct (0..7)
  int dp = w * 8 + ((t & 63) >> 3);
  int koct = t & 7;
  const unsigned* vg32 = (const unsigned*)vb + ((size_t)(ktbase * 64 + koct * 8)) * 32 + dp;

  // preload first tile into regs
  short8 kr0 = *(const short8*)(kg);
  short8 kr1 = *(const short8*)(kg + 8);
  unsigned lv[8];
#pragma unroll
  for (int kk = 0; kk < 8; kk++) lv[kk] = vg32[(size_t)kk * 32];

  for (int i = 0; i < 12; i++) {
    __syncthreads();
    *(short8*)&Ks[srow][scol] = kr0;
    *(short8*)&Ks[srow][scol + 8] = kr1;
    {
      u32x4 ev = {pack_lo16(lv[1], lv[0]), pack_lo16(lv[3], lv[2]),
                  pack_lo16(lv[5], lv[4]), pack_lo16(lv[7], lv[6])};
      u32x4 od = {pack_hi16(lv[1], lv[0]), pack_hi16(lv[3], lv[2]),
                  pack_hi16(lv[5], lv[4]), pack_hi16(lv[7], lv[6])};
      *(u32x4*)&Vs[2 * dp][koct * 8] = ev;
      *(u32x4*)&Vs[2 * dp + 1][koct * 8] = od;
    }
    __syncthreads();
    if (i < 11) {  // prefetch next tile; latency hides under compute below
      size_t koff = (size_t)(i + 1) * 64 * DH_;
      kr0 = *(const short8*)(kg + koff);
      kr1 = *(const short8*)(kg + koff + 8);
      const unsigned* vg = vg32 + (size_t)(i + 1) * 64 * 32;
#pragma unroll
      for (int kk = 0; kk < 8; kk++) lv[kk] = vg[(size_t)kk * 32];
    }
    // S^T = K Q^T : A = K-tile (m=key), B = Q regs (n=query)
    f32x16 sc0, sc1;
    {
      short8 a0 = *(const short8*)&Ks[l31][hi * 8];
      short8 a1 = *(const short8*)&Ks[32 + l31][hi * 8];
      sc0 = __builtin_amdgcn_mfma_f32_32x32x16_bf16(as_bf(a0), as_bf(qf[0]), z16, 0, 0, 0);
      sc1 = __builtin_amdgcn_mfma_f32_32x32x16_bf16(as_bf(a1), as_bf(qf[0]), z16, 0, 0, 0);
    }
#pragma unroll
    for (int ks = 1; ks < 4; ks++) {
      short8 a0 = *(const short8*)&Ks[l31][ks * 16 + hi * 8];
      short8 a1 = *(const short8*)&Ks[32 + l31][ks * 16 + hi * 8];
      sc0 = __builtin_amdgcn_mfma_f32_32x32x16_bf16(as_bf(a0), as_bf(qf[ks]), sc0, 0, 0, 0);
      sc1 = __builtin_amdgcn_mfma_f32_32x32x16_bf16(as_bf(a1), as_bf(qf[ks]), sc1, 0, 0, 0);
    }
    // exp2 numerator; half-up bf16 pack; P^T -> per-wave LDS
    float lsum = 0.f;
#pragma unroll
    for (int mt = 0; mt < 2; mt++) {
      const f32x16& s = mt ? sc1 : sc0;
#pragma unroll
      for (int g = 0; g < 4; g++) {
        float e0 = fexp2(s[g * 4 + 0] - shift2);
        float e1 = fexp2(s[g * 4 + 1] - shift2);
        float e2 = fexp2(s[g * 4 + 2] - shift2);
        float e3 = fexp2(s[g * 4 + 3] - shift2);
        lsum += (e0 + e1) + (e2 + e3);
        unsigned u0 = __builtin_bit_cast(unsigned, e0) + 0x8000u;
        unsigned u1 = __builtin_bit_cast(unsigned, e1) + 0x8000u;
        unsigned u2 = __builtin_bit_cast(unsigned, e2) + 0x8000u;
        unsigned u3 = __builtin_bit_cast(unsigned, e3) + 0x8000u;
        u32x2 pk = {pack_hi16(u1, u0), pack_hi16(u3, u2)};
        *(u32x2*)&Ps[w][l31][mt * 32 + g * 8 + hi * 4] = pk;
      }
    }
    l_part += lsum;
    // O^T += V^T P^T : A = V-tile (m=d), B = P (n=query) — same-wave LDS, no barrier
#pragma unroll
    for (int ks = 0; ks < 4; ks++) {
      short8 pb = *(const short8*)&Ps[w][l31][ks * 16 + hi * 8];
      short8 va0 = *(const short8*)&Vs[l31][ks * 16 + hi * 8];
      short8 va1 = *(const short8*)&Vs[32 + l31][ks * 16 + hi * 8];
      O0 = __builtin_amdgcn_mfma_f32_32x32x16_bf16(as_bf(va0), as_bf(pb), O0, 0, 0, 0);
      O1 = __builtin_amdgcn_mfma_f32_32x32x16_bf16(as_bf(va1), as_bf(pb), O1, 0, 0, 0);
    }
  }
  float l = l_part + __shfl_xor(l_part, 32);
  if (hi == 0) lp[((size_t)(split * 16 + bh)) * S_ + q0 + l31] = l;
  unsigned short* orow = attnp + (((size_t)(split * 16 + bh)) * S_ + q0 + l31) * DH_;
#pragma unroll
  for (int mt = 0; mt < 2; mt++) {
    const f32x16& O = mt ? O1 : O0;
#pragma unroll
    for (int g = 0; g < 4; g++) {
      us4 o4 = {f2bf(O[g * 4 + 0]), f2bf(O[g * 4 + 1]), f2bf(O[g * 4 + 2]), f2bf(O[g * 4 + 3])};
      *(us4*)&orow[mt * 32 + g * 8 + hi * 4] = o4;
    }
  }
}

// ---------------- K4: depthwise 3x3 with 3-way split-combine + normalize ----------------
// Grid (bh, pblk): bh fastest -> XCD pinned per bh (attnp slices L2-resident).
__global__ __launch_bounds__(256) void k_dwconv(const unsigned short* __restrict__ attnp,
                                                const float* __restrict__ lp,
                                                const float* __restrict__ w_dw,
                                                unsigned short* __restrict__ dwb) {
  int t = threadIdx.x;
  int d = t & 63;
  int pj = t >> 6;
  int p = blockIdx.y * 4 + pj;
  int bh = blockIdx.x;
  int b = bh >> 3, h = bh & 7;
  int yy = p / 48, xx = p % 48;
  const unsigned short* a0 = attnp + (size_t)bh * S_ * DH_ + d;
  const unsigned short* a1 = attnp + ((size_t)(16 + bh)) * S_ * DH_ + d;
  const unsigned short* a2 = attnp + ((size_t)(32 + bh)) * S_ * DH_ + d;
  const float* l0 = lp + (size_t)bh * S_;
  const float* l1 = lp + (size_t)(16 + bh) * S_;
  const float* l2 = lp + (size_t)(32 + bh) * S_;
  int ch = h * 64 + d;
  float w[9];
#pragma unroll
  for (int i = 0; i < 9; i++) w[i] = w_dw[ch * 9 + i];
  float acc = 0.f;
#pragma unroll
  for (int dy = -1; dy <= 1; dy++) {
    int y2 = yy + dy;
    if (y2 < 0 || y2 >= 48) continue;
#pragma unroll
    for (int dx = -1; dx <= 1; dx++) {
      int x2 = xx + dx;
      if (x2 < 0 || x2 >= 48) continue;
      int p2 = y2 * 48 + x2;  // wave-uniform
      float rl = frcp(l0[p2] + l1[p2] + l2[p2]);
      float v = (bf2f(a0[(size_t)p2 * DH_]) + bf2f(a1[(size_t)p2 * DH_]) + bf2f(a2[(size_t)p2 * DH_])) * rl;
      acc += v * w[(dy + 1) * 3 + dx + 1];
    }
  }
  dwb[((size_t)b * S_ + p) * INNER_ + ch] = f2bf(acc);
}

// ---------------- K6: channel LN + scales/shifts + final ----------------
// 16 positions/block, float2 per thread: 64B coalesced segments. Grid (144, 2).
__global__ __launch_bounds__(256) void k_ln_final(const float* __restrict__ pw,
                                                  const float* __restrict__ gamma,
                                                  const float* __restrict__ beta,
                                                  const float* __restrict__ x,
                                                  float* __restrict__ out) {
  __shared__ float s_s0[32][8], s_s1[32][8], s_q0[32][8], s_q1[32][8];
  int t = threadIdx.x;
  int pl = t & 7, g = t >> 3;               // 8 position-pairs x 32 channel-groups
  int b = blockIdx.y;
  int p = blockIdx.x * 16 + pl * 2;
  const float* pwb = pw + (size_t)b * INNER_ * S_ + p;
  float s0 = 0.f, s1 = 0.f, q0 = 0.f, q1 = 0.f;
#pragma unroll
  for (int j = 0; j < 16; j++) {
    float2 v = *(const float2*)&pwb[(size_t)(g * 16 + j) * S_];
    s0 += v.x; s1 += v.y;
    q0 += v.x * v.x; q1 += v.y * v.y;
  }
  s_s0[g][pl] = s0; s_s1[g][pl] = s1;
  s_q0[g][pl] = q0; s_q1[g][pl] = q1;
  __syncthreads();
  float t0 = 0.f, t1 = 0.f, u0 = 0.f, u1 = 0.f;
#pragma unroll
  for (int i = 0; i < 32; i++) {
    t0 += s_s0[i][pl]; t1 += s_s1[i][pl];
    u0 += s_q0[i][pl]; u1 += s_q1[i][pl];
  }
  float mu0 = t0 * (1.f / 512.f), mu1 = t1 * (1.f / 512.f);
  float rs0 = rsqrtf(u0 * (1.f / 512.f) - mu0 * mu0 + 1e-5f);
  float rs1 = rsqrtf(u1 * (1.f / 512.f) - mu1 * mu1 + 1e-5f);
  const float* xb = x + (size_t)b * C_ * S_ + p;
  float* ob = out + (size_t)b * C_ * S_ + p;
#pragma unroll
  for (int j = 0; j < 8; j++) {
    int cc = g * 8 + j;  // 0..255
    float ga = gamma[cc], be = beta[cc];
    float gs = gamma[cc + 256], bs = beta[cc + 256];
    float2 pv = *(const float2*)&pwb[(size_t)cc * S_];
    float2 sv = *(const float2*)&pwb[(size_t)(cc + 256) * S_];
    float2 xv = *(const float2*)&xb[(size_t)cc * S_];
    float sc0 = (pv.x - mu0) * rs0 * ga + be;
    float sc1 = (pv.y - mu1) * rs1 * ga + be;
    float sh0 = (sv.x - mu0) * rs0 * gs + bs;
    float sh1 = (sv.y - mu1) * rs1 * gs + bs;
    float2 o;
    o.x = sh0 + xv.x * sc0;
    o.y = sh1 + xv.y * sc1;
    *(float2*)&ob[(size_t)cc * S_] = o;
  }
}

extern "C" void kernel_launch(void* const* d_in, const int* in_sizes, int n_in,
                              void* d_out, int out_size, void* d_ws, size_t ws_size,
                              hipStream_t stream) {
  const float* x = (const float*)d_in[0];
  const float* w_in = (const float*)d_in[1];
  const float* b_in = (const float*)d_in[2];
  const float* ss = (const float*)d_in[3];
  const float* w_dw = (const float*)d_in[4];
  const float* w_pw = (const float*)d_in[5];
  const float* gamma = (const float*)d_in[6];
  const float* beta = (const float*)d_in[7];
  float* out = (float*)d_out;
  char* ws = (char*)d_ws;

  unsigned short* xT = (unsigned short*)(ws + 0);           // 2,359,296
  unsigned short* w_inb = (unsigned short*)(ws + 2359296);  // 786,432
  unsigned short* w_pwb = (unsigned short*)(ws + 3145728);  // 524,288
  unsigned short* qn = (unsigned short*)(ws + 3670016);     // 4,718,592
  unsigned short* kn = (unsigned short*)(ws + 8388608);     // 4,718,592
  unsigned short* vv = (unsigned short*)(ws + 13107200);    // 4,718,592  [bh][p][d]
  unsigned short* dwb = (unsigned short*)(ws + 17825792);   // 4,718,592
  float* lp = (float*)(ws + 22544384);                      // 442,368  [3][16][2304] fp32
  unsigned short* attnp = (unsigned short*)(ws + 22986752); // bf16 [3][16][2304][64] = 14,155,776
  float* pw = (float*)(ws + 37142528);                      // fp32 [2][512][2304] = 9,437,184

  k_prep<<<2848, 256, 0, stream>>>(x, w_in, w_pw, xT, w_inb, w_pwb);
  k_gemm_qkv<<<dim3(18, 24, 2), 256, 0, stream>>>(w_inb, xT, b_in, ss, qn, kn, vv);
  k_attn<<<dim3(16, 18, 3), 256, 0, stream>>>(qn, kn, vv, ss, attnp, lp);
  k_dwconv<<<dim3(16, 576), 256, 0, stream>>>(attnp, lp, w_dw, dwb);
  k_gemm2<<<dim3(36, 8, 2), 128, 0, stream>>>(w_pwb, dwb, pw, INNER_, S_, INNER_);
  k_ln_final<<<dim3(144, 2), 256, 0, stream>>>(pw, gamma, beta, x, out);
}

// Round 11
// 165.735 us; speedup vs baseline: 1.3287x; 1.0369x over previous
//
#include <hip/hip_runtime.h>

#define B_ 2
#define C_ 256
#define S_ 2304
#define DH_ 64
#define O3_ 1536
#define INNER_ 512
#define LOGSMAX 4.605170185988092f
#define LOG2E 1.4426950408889634f

typedef __attribute__((ext_vector_type(8))) short short8;
typedef __attribute__((ext_vector_type(4))) float f32x4;
typedef __attribute__((ext_vector_type(16))) float f32x16;
typedef __attribute__((ext_vector_type(4))) unsigned short us4;
typedef __attribute__((ext_vector_type(2))) unsigned u32x2;
typedef __attribute__((ext_vector_type(4))) unsigned u32x4;
typedef __bf16 bf16x8 __attribute__((ext_vector_type(8)));

__device__ __forceinline__ unsigned short f2bf(float f) {
  unsigned u = __builtin_bit_cast(unsigned, f);
  u += 0x7FFFu + ((u >> 16) & 1u);
  return (unsigned short)(u >> 16);
}
__device__ __forceinline__ float bf2f(unsigned short h) {
  return __builtin_bit_cast(float, (unsigned)h << 16);
}
__device__ __forceinline__ bf16x8 as_bf(short8 v) {
  return __builtin_bit_cast(bf16x8, v);
}
__device__ __forceinline__ float fexp2(float x) {
#if __has_builtin(__builtin_amdgcn_exp2f)
  return __builtin_amdgcn_exp2f(x);
#else
  return __expf(x * 0.6931471805599453f);
#endif
}
__device__ __forceinline__ float frcp(float x) {
#if __has_builtin(__builtin_amdgcn_rcpf)
  return __builtin_amdgcn_rcpf(x);
#else
  return 1.f / x;
#endif
}
// pack hi16 of two fp32 bit-patterns: (hi16(b)<<16)|hi16(a) — 1 v_perm_b32
__device__ __forceinline__ unsigned pack_hi16(unsigned b, unsigned a) {
  return __builtin_amdgcn_perm(b, a, 0x07060302u);
}
// pack lo16: (lo16(b)<<16)|lo16(a)
__device__ __forceinline__ unsigned pack_lo16(unsigned b, unsigned a) {
  return __builtin_amdgcn_perm(b, a, 0x05040100u);
}

// ---------------- K0: fused prep: x transpose + both weight converts ----------------
__global__ __launch_bounds__(256) void k_prep(const float* __restrict__ x,
                                              const float* __restrict__ w_in,
                                              const float* __restrict__ w_pw,
                                              unsigned short* __restrict__ xT,
                                              unsigned short* __restrict__ w_inb,
                                              unsigned short* __restrict__ w_pwb) {
  __shared__ float tile[64][65];
  int blk = blockIdx.x;
  int t = threadIdx.x;
  if (blk < 288) {  // transpose x [b][c][p] -> xT [b][p][c] bf16
    int p0 = (blk % 36) * 64, c0 = ((blk / 36) % 4) * 64, b = blk / 144;
    const float* xb = x + (size_t)b * C_ * S_;
#pragma unroll
    for (int i = 0; i < 16; i++) {
      int c = i * 4 + (t >> 6);
      int p = t & 63;
      tile[c][p] = xb[(size_t)(c0 + c) * S_ + p0 + p];
    }
    __syncthreads();
    unsigned short* xTb = xT + (size_t)b * S_ * C_;
#pragma unroll
    for (int i = 0; i < 16; i++) {
      int p = i * 4 + (t >> 6);
      int c = t & 63;
      xTb[(size_t)(p0 + p) * C_ + c0 + c] = f2bf(tile[c][p]);
    }
  } else if (blk < 288 + 1536) {
    int i = (blk - 288) * 256 + t;
    w_inb[i] = f2bf(w_in[i]);
  } else {
    int i = (blk - 1824) * 256 + t;
    w_pwb[i] = f2bf(w_pw[i]);
  }
}

// ---------------- K1: proj_in GEMM with fused bias + l2norm + scale epilogue ----------------
// 64x128 tile; M-tile 64 == one (head, q/k/v-seg) channel group.
// Writes qn/kn fp8 [bh][p][64] (scale*log2e folded into q), vv bf16 [bh][p][64].
__global__ __launch_bounds__(256) void k_gemm_qkv(const unsigned short* __restrict__ A,
                                                  const unsigned short* __restrict__ BT,
                                                  const float* __restrict__ b_in,
                                                  const float* __restrict__ ss,
                                                  unsigned char* __restrict__ qn,
                                                  unsigned char* __restrict__ kn,
                                                  unsigned short* __restrict__ vv) {
  __shared__ __align__(16) unsigned short As[64][72];
  __shared__ __align__(16) unsigned short Bs[128][72];
  int t = threadIdx.x;
  int lane = t & 63, wv = t >> 6;
  int quad = lane >> 4, r15 = lane & 15;
  int by = blockIdx.y;
  int m0 = by * 64, n0 = blockIdx.x * 128;
  int b = blockIdx.z;
  const unsigned short* BTb = BT + (size_t)b * S_ * C_;

  f32x4 acc[4][2] = {};

  int srA = t >> 2, scA = (t & 3) * 16;
  int srB = t >> 1, scB = (t & 1) * 32;
  const unsigned short* ag = A + (size_t)(m0 + srA) * C_ + scA;
  const unsigned short* bg = BTb + (size_t)(n0 + srB) * C_ + scB;

  for (int k0 = 0; k0 < C_; k0 += 64) {
    short8 a0 = *(const short8*)(ag + k0);
    short8 a1 = *(const short8*)(ag + k0 + 8);
    short8 b0 = *(const short8*)(bg + k0);
    short8 b1 = *(const short8*)(bg + k0 + 8);
    short8 b2 = *(const short8*)(bg + k0 + 16);
    short8 b3 = *(const short8*)(bg + k0 + 24);
    __syncthreads();
    *(short8*)&As[srA][scA] = a0;
    *(short8*)&As[srA][scA + 8] = a1;
    *(short8*)&Bs[srB][scB] = b0;
    *(short8*)&Bs[srB][scB + 8] = b1;
    *(short8*)&Bs[srB][scB + 16] = b2;
    *(short8*)&Bs[srB][scB + 24] = b3;
    __syncthreads();
#pragma unroll
    for (int ks = 0; ks < 2; ks++) {
      short8 af[4], bfr[2];
#pragma unroll
      for (int i = 0; i < 4; i++) af[i] = *(const short8*)&As[i * 16 + r15][ks * 32 + quad * 8];
#pragma unroll
      for (int j = 0; j < 2; j++) bfr[j] = *(const short8*)&Bs[wv * 32 + j * 16 + r15][ks * 32 + quad * 8];
#pragma unroll
      for (int i = 0; i < 4; i++)
#pragma unroll
        for (int j = 0; j < 2; j++)
          acc[i][j] = __builtin_amdgcn_mfma_f32_16x16x32_bf16(as_bf(af[i]), as_bf(bfr[j]), acc[i][j], 0, 0, 0);
    }
  }

  // epilogue: bias add, per-position l2norm (q/k) -> fp8; v -> bf16
  int h = by / 3, seg = by - h * 3;
  int bh = b * 8 + h;
  f32x4 bi[4];
#pragma unroll
  for (int i = 0; i < 4; i++) bi[i] = *(const f32x4*)&b_in[m0 + i * 16 + quad * 4];
  float bv[4][2][4];
  float ssq0 = 0.f, ssq1 = 0.f;
#pragma unroll
  for (int i = 0; i < 4; i++)
#pragma unroll
    for (int rr = 0; rr < 4; rr++) {
      float v0 = acc[i][0][rr] + bi[i][rr];
      float v1 = acc[i][1][rr] + bi[i][rr];
      bv[i][0][rr] = v0;
      bv[i][1][rr] = v1;
      ssq0 += v0 * v0;
      ssq1 += v1 * v1;
    }
  if (seg < 2) {
    float sc = (seg == 0) ? __expf(fminf(ss[h], LOGSMAX)) * LOG2E : 1.f;
    ssq0 += __shfl_xor(ssq0, 16);
    ssq0 += __shfl_xor(ssq0, 32);
    ssq1 += __shfl_xor(ssq1, 16);
    ssq1 += __shfl_xor(ssq1, 32);
    float inv0 = sc / fmaxf(sqrtf(ssq0), 1e-12f);
    float inv1 = sc / fmaxf(sqrtf(ssq1), 1e-12f);
    unsigned char* dst = (seg == 0 ? qn : kn) + (size_t)bh * S_ * DH_;
#pragma unroll
    for (int i = 0; i < 4; i++)
#pragma unroll
      for (int j = 0; j < 2; j++) {
        float iv = j ? inv1 : inv0;
        int pk = __builtin_amdgcn_cvt_pk_fp8_f32(bv[i][j][0] * iv, bv[i][j][1] * iv, 0, false);
        pk = __builtin_amdgcn_cvt_pk_fp8_f32(bv[i][j][2] * iv, bv[i][j][3] * iv, pk, true);
        int p = n0 + wv * 32 + j * 16 + r15;
        *(int*)&dst[(size_t)p * DH_ + i * 16 + quad * 4] = pk;
      }
  } else {
    unsigned short* dst = vv + (size_t)bh * S_ * DH_;
#pragma unroll
    for (int i = 0; i < 4; i++)
#pragma unroll
      for (int j = 0; j < 2; j++) {
        us4 o = {f2bf(bv[i][j][0]), f2bf(bv[i][j][1]), f2bf(bv[i][j][2]), f2bf(bv[i][j][3])};
        int p = n0 + wv * 32 + j * 16 + r15;
        *(us4*)&dst[(size_t)p * DH_ + i * 16 + quad * 4] = o;
      }
  }
}

// ---------------- K5: pw GEMM, 64x64 tile, 2 waves ----------------
__global__ __launch_bounds__(128) void k_gemm2(const unsigned short* __restrict__ A,
                                               const unsigned short* __restrict__ BT,
                                               float* __restrict__ outp,
                                               int M, int N, int K) {
  __shared__ __align__(16) unsigned short As[64][72];
  __shared__ __align__(16) unsigned short Bs[64][72];
  int t = threadIdx.x;
  int lane = t & 63, wv = t >> 6;
  int quad = lane >> 4, r15 = lane & 15;
  int m0 = blockIdx.y * 64, n0 = blockIdx.x * 64;
  int b = blockIdx.z;
  const unsigned short* BTb = BT + (size_t)b * N * K;

  f32x4 acc[4][2] = {};

  int sr = t >> 1, sc = (t & 1) * 32;
  const unsigned short* ag = A + (size_t)(m0 + sr) * K + sc;
  const unsigned short* bg = BTb + (size_t)(n0 + sr) * K + sc;

  for (int k0 = 0; k0 < K; k0 += 64) {
    short8 a0 = *(const short8*)(ag + k0);
    short8 a1 = *(const short8*)(ag + k0 + 8);
    short8 a2 = *(const short8*)(ag + k0 + 16);
    short8 a3 = *(const short8*)(ag + k0 + 24);
    short8 b0 = *(const short8*)(bg + k0);
    short8 b1 = *(const short8*)(bg + k0 + 8);
    short8 b2 = *(const short8*)(bg + k0 + 16);
    short8 b3 = *(const short8*)(bg + k0 + 24);
    __syncthreads();
    *(short8*)&As[sr][sc] = a0;
    *(short8*)&As[sr][sc + 8] = a1;
    *(short8*)&As[sr][sc + 16] = a2;
    *(short8*)&As[sr][sc + 24] = a3;
    *(short8*)&Bs[sr][sc] = b0;
    *(short8*)&Bs[sr][sc + 8] = b1;
    *(short8*)&Bs[sr][sc + 16] = b2;
    *(short8*)&Bs[sr][sc + 24] = b3;
    __syncthreads();
#pragma unroll
    for (int ks = 0; ks < 2; ks++) {
      short8 af[4], bfr[2];
#pragma unroll
      for (int i = 0; i < 4; i++) af[i] = *(const short8*)&As[i * 16 + r15][ks * 32 + quad * 8];
#pragma unroll
      for (int j = 0; j < 2; j++) bfr[j] = *(const short8*)&Bs[wv * 32 + j * 16 + r15][ks * 32 + quad * 8];
#pragma unroll
      for (int i = 0; i < 4; i++)
#pragma unroll
        for (int j = 0; j < 2; j++)
          acc[i][j] = __builtin_amdgcn_mfma_f32_16x16x32_bf16(as_bf(af[i]), as_bf(bfr[j]), acc[i][j], 0, 0, 0);
    }
  }
  float* Cb = outp + (size_t)b * M * N;
#pragma unroll
  for (int i = 0; i < 4; i++)
#pragma unroll
    for (int j = 0; j < 2; j++)
#pragma unroll
      for (int rr = 0; rr < 4; rr++) {
        int row = m0 + i * 16 + quad * 4 + rr;
        int col = n0 + wv * 32 + j * 16 + r15;
        Cb[(size_t)row * N + col] = acc[i][j][rr];
      }
}

// ---------------- K3: hybrid attention: Q/K fp8 (S^T MFMA), P/V bf16 (O MFMA) ----------------
// 32x32 MFMA, 4 waves x 32q, LDS K/V shared, split-K x3.
// Grid (bh, qtile, split): bh fastest -> XCD = bh%8 pinned.
__global__ __launch_bounds__(256) void k_attn(const unsigned char* __restrict__ qn,
                                              const unsigned char* __restrict__ kn,
                                              const unsigned short* __restrict__ vv,
                                              const float* __restrict__ ss,
                                              unsigned short* __restrict__ attnp,
                                              float* __restrict__ lp) {
  __shared__ __align__(16) unsigned char Ks[64][72];       // [key][d] fp8 (stride 18dw: 2-way free)
  __shared__ __align__(16) unsigned short Vs[64][72];      // [d][key] bf16
  __shared__ __align__(16) unsigned short Ps[4][32][76];   // per wave [q][key] bf16
  int t = threadIdx.x;
  int w = t >> 6;
  int lane = t & 63;
  int l31 = lane & 31, hi = lane >> 5;
  int bh = blockIdx.x;
  int q0 = blockIdx.y * 128 + w * 32;
  int split = blockIdx.z;
  int ktbase = split * 12;
  const unsigned char* qb = qn + (size_t)bh * S_ * DH_;
  const unsigned char* kb = kn + (size_t)bh * S_ * DH_;
  const unsigned short* vb = vv + (size_t)bh * S_ * DH_;
  float shift2 = __expf(fminf(ss[bh & 7], LOGSMAX)) * LOG2E;  // |s'| <= shift2

  // Q as fp8 B-fragment: n=query=l31, k(d) = ks*16 + hi*8 + j
  const unsigned char* qrow = qb + (size_t)(q0 + l31) * DH_ + hi * 8;
  long qf[4];
#pragma unroll
  for (int ks = 0; ks < 4; ks++) qf[ks] = *(const long*)(qrow + ks * 16);

  const f32x16 z16 = {};
  f32x16 O0 = z16, O1 = z16;
  float l_part = 0.f;

  // K staging: 256 threads cover 64key x 64B fp8 tile, 16B each
  int srow = t >> 2;          // 0..63 (key)
  int scol = (t & 3) * 16;    // d byte
  const unsigned char* kg = kb + ((size_t)(ktbase * 64) + srow) * DH_ + scol;

  // V transpose staging: thread -> d-pair dp (0..31), key-octet koct (0..7)
  int dp = w * 8 + ((t & 63) >> 3);
  int koct = t & 7;
  const unsigned* vg32 = (const unsigned*)vb + ((size_t)(ktbase * 64 + koct * 8)) * 32 + dp;

  // preload first tile into regs
  uint4 kr = *(const uint4*)kg;
  unsigned lv[8];
#pragma unroll
  for (int kk = 0; kk < 8; kk++) lv[kk] = vg32[(size_t)kk * 32];

  for (int i = 0; i < 12; i++) {
    __syncthreads();
    *(uint4*)&Ks[srow][scol] = kr;
    {
      u32x4 ev = {pack_lo16(lv[1], lv[0]), pack_lo16(lv[3], lv[2]),
                  pack_lo16(lv[5], lv[4]), pack_lo16(lv[7], lv[6])};
      u32x4 od = {pack_hi16(lv[1], lv[0]), pack_hi16(lv[3], lv[2]),
                  pack_hi16(lv[5], lv[4]), pack_hi16(lv[7], lv[6])};
      *(u32x4*)&Vs[2 * dp][koct * 8] = ev;
      *(u32x4*)&Vs[2 * dp + 1][koct * 8] = od;
    }
    __syncthreads();
    if (i < 11) {  // prefetch next tile; latency hides under compute below
      kr = *(const uint4*)(kg + (size_t)(i + 1) * 64 * DH_);
      const unsigned* vg = vg32 + (size_t)(i + 1) * 64 * 32;
#pragma unroll
      for (int kk = 0; kk < 8; kk++) lv[kk] = vg[(size_t)kk * 32];
    }
    // S^T = K Q^T : A = K fp8 frags (m=key), B = Q fp8 regs (n=query)
    f32x16 sc0, sc1;
    {
      long a0 = *(const long*)&Ks[l31][hi * 8];
      long a1 = *(const long*)&Ks[32 + l31][hi * 8];
      sc0 = __builtin_amdgcn_mfma_f32_32x32x16_fp8_fp8(a0, qf[0], z16, 0, 0, 0);
      sc1 = __builtin_amdgcn_mfma_f32_32x32x16_fp8_fp8(a1, qf[0], z16, 0, 0, 0);
    }
#pragma unroll
    for (int ks = 1; ks < 4; ks++) {
      long a0 = *(const long*)&Ks[l31][ks * 16 + hi * 8];
      long a1 = *(const long*)&Ks[32 + l31][ks * 16 + hi * 8];
      sc0 = __builtin_amdgcn_mfma_f32_32x32x16_fp8_fp8(a0, qf[ks], sc0, 0, 0, 0);
      sc1 = __builtin_amdgcn_mfma_f32_32x32x16_fp8_fp8(a1, qf[ks], sc1, 0, 0, 0);
    }
    // exp2 numerator; half-up bf16 pack; P^T -> per-wave LDS
    float lsum = 0.f;
#pragma unroll
    for (int mt = 0; mt < 2; mt++) {
      const f32x16& s = mt ? sc1 : sc0;
#pragma unroll
      for (int g = 0; g < 4; g++) {
        float e0 = fexp2(s[g * 4 + 0] - shift2);
        float e1 = fexp2(s[g * 4 + 1] - shift2);
        float e2 = fexp2(s[g * 4 + 2] - shift2);
        float e3 = fexp2(s[g * 4 + 3] - shift2);
        lsum += (e0 + e1) + (e2 + e3);
        unsigned u0 = __builtin_bit_cast(unsigned, e0) + 0x8000u;
        unsigned u1 = __builtin_bit_cast(unsigned, e1) + 0x8000u;
        unsigned u2 = __builtin_bit_cast(unsigned, e2) + 0x8000u;
        unsigned u3 = __builtin_bit_cast(unsigned, e3) + 0x8000u;
        u32x2 pk = {pack_hi16(u1, u0), pack_hi16(u3, u2)};
        *(u32x2*)&Ps[w][l31][mt * 32 + g * 8 + hi * 4] = pk;
      }
    }
    l_part += lsum;
    // O^T += V^T P^T : A = V bf16 tile (m=d), B = P bf16 (n=query) — same-wave LDS, no barrier
#pragma unroll
    for (int ks = 0; ks < 4; ks++) {
      short8 pb = *(const short8*)&Ps[w][l31][ks * 16 + hi * 8];
      short8 va0 = *(const short8*)&Vs[l31][ks * 16 + hi * 8];
      short8 va1 = *(const short8*)&Vs[32 + l31][ks * 16 + hi * 8];
      O0 = __builtin_amdgcn_mfma_f32_32x32x16_bf16(as_bf(va0), as_bf(pb), O0, 0, 0, 0);
      O1 = __builtin_amdgcn_mfma_f32_32x32x16_bf16(as_bf(va1), as_bf(pb), O1, 0, 0, 0);
    }
  }
  float l = l_part + __shfl_xor(l_part, 32);
  if (hi == 0) lp[((size_t)(split * 16 + bh)) * S_ + q0 + l31] = l;
  unsigned short* orow = attnp + (((size_t)(split * 16 + bh)) * S_ + q0 + l31) * DH_;
#pragma unroll
  for (int mt = 0; mt < 2; mt++) {
    const f32x16& O = mt ? O1 : O0;
#pragma unroll
    for (int g = 0; g < 4; g++) {
      us4 o4 = {f2bf(O[g * 4 + 0]), f2bf(O[g * 4 + 1]), f2bf(O[g * 4 + 2]), f2bf(O[g * 4 + 3])};
      *(us4*)&orow[mt * 32 + g * 8 + hi * 4] = o4;
    }
  }
}

// ---------------- K4: depthwise 3x3 with 3-way split-combine + normalize ----------------
// Grid (bh, pblk): bh fastest -> XCD pinned per bh.
__global__ __launch_bounds__(256) void k_dwconv(const unsigned short* __restrict__ attnp,
                                                const float* __restrict__ lp,
                                                const float* __restrict__ w_dw,
                                                unsigned short* __restrict__ dwb) {
  int t = threadIdx.x;
  int d = t & 63;
  int pj = t >> 6;
  int p = blockIdx.y * 4 + pj;
  int bh = blockIdx.x;
  int b = bh >> 3, h = bh & 7;
  int yy = p / 48, xx = p % 48;
  const unsigned short* a0 = attnp + (size_t)bh * S_ * DH_ + d;
  const unsigned short* a1 = attnp + ((size_t)(16 + bh)) * S_ * DH_ + d;
  const unsigned short* a2 = attnp + ((size_t)(32 + bh)) * S_ * DH_ + d;
  const float* l0 = lp + (size_t)bh * S_;
  const float* l1 = lp + (size_t)(16 + bh) * S_;
  const float* l2 = lp + (size_t)(32 + bh) * S_;
  int ch = h * 64 + d;
  float w[9];
#pragma unroll
  for (int i = 0; i < 9; i++) w[i] = w_dw[ch * 9 + i];
  float acc = 0.f;
#pragma unroll
  for (int dy = -1; dy <= 1; dy++) {
    int y2 = yy + dy;
    if (y2 < 0 || y2 >= 48) continue;
#pragma unroll
    for (int dx = -1; dx <= 1; dx++) {
      int x2 = xx + dx;
      if (x2 < 0 || x2 >= 48) continue;
      int p2 = y2 * 48 + x2;  // wave-uniform
      float rl = frcp(l0[p2] + l1[p2] + l2[p2]);
      float v = (bf2f(a0[(size_t)p2 * DH_]) + bf2f(a1[(size_t)p2 * DH_]) + bf2f(a2[(size_t)p2 * DH_])) * rl;
      acc += v * w[(dy + 1) * 3 + dx + 1];
    }
  }
  dwb[((size_t)b * S_ + p) * INNER_ + ch] = f2bf(acc);
}

// ---------------- K6: channel LN + scales/shifts + final ----------------
__global__ __launch_bounds__(256) void k_ln_final(const float* __restrict__ pw,
                                                  const float* __restrict__ gamma,
                                                  const float* __restrict__ beta,
                                                  const float* __restrict__ x,
                                                  float* __restrict__ out) {
  __shared__ float s_s0[32][8], s_s1[32][8], s_q0[32][8], s_q1[32][8];
  int t = threadIdx.x;
  int pl = t & 7, g = t >> 3;
  int b = blockIdx.y;
  int p = blockIdx.x * 16 + pl * 2;
  const float* pwb = pw + (size_t)b * INNER_ * S_ + p;
  float s0 = 0.f, s1 = 0.f, q0 = 0.f, q1 = 0.f;
#pragma unroll
  for (int j = 0; j < 16; j++) {
    float2 v = *(const float2*)&pwb[(size_t)(g * 16 + j) * S_];
    s0 += v.x; s1 += v.y;
    q0 += v.x * v.x; q1 += v.y * v.y;
  }
  s_s0[g][pl] = s0; s_s1[g][pl] = s1;
  s_q0[g][pl] = q0; s_q1[g][pl] = q1;
  __syncthreads();
  float t0 = 0.f, t1 = 0.f, u0 = 0.f, u1 = 0.f;
#pragma unroll
  for (int i = 0; i < 32; i++) {
    t0 += s_s0[i][pl]; t1 += s_s1[i][pl];
    u0 += s_q0[i][pl]; u1 += s_q1[i][pl];
  }
  float mu0 = t0 * (1.f / 512.f), mu1 = t1 * (1.f / 512.f);
  float rs0 = rsqrtf(u0 * (1.f / 512.f) - mu0 * mu0 + 1e-5f);
  float rs1 = rsqrtf(u1 * (1.f / 512.f) - mu1 * mu1 + 1e-5f);
  const float* xb = x + (size_t)b * C_ * S_ + p;
  float* ob = out + (size_t)b * C_ * S_ + p;
#pragma unroll
  for (int j = 0; j < 8; j++) {
    int cc = g * 8 + j;
    float ga = gamma[cc], be = beta[cc];
    float gs = gamma[cc + 256], bs = beta[cc + 256];
    float2 pv = *(const float2*)&pwb[(size_t)cc * S_];
    float2 sv = *(const float2*)&pwb[(size_t)(cc + 256) * S_];
    float2 xv = *(const float2*)&xb[(size_t)cc * S_];
    float sc0 = (pv.x - mu0) * rs0 * ga + be;
    float sc1 = (pv.y - mu1) * rs1 * ga + be;
    float sh0 = (sv.x - mu0) * rs0 * gs + bs;
    float sh1 = (sv.y - mu1) * rs1 * gs + bs;
    float2 o;
    o.x = sh0 + xv.x * sc0;
    o.y = sh1 + xv.y * sc1;
    *(float2*)&ob[(size_t)cc * S_] = o;
  }
}

extern "C" void kernel_launch(void* const* d_in, const int* in_sizes, int n_in,
                              void* d_out, int out_size, void* d_ws, size_t ws_size,
                              hipStream_t stream) {
  const float* x = (const float*)d_in[0];
  const float* w_in = (const float*)d_in[1];
  const float* b_in = (const float*)d_in[2];
  const float* ss = (const float*)d_in[3];
  const float* w_dw = (const float*)d_in[4];
  const float* w_pw = (const float*)d_in[5];
  const float* gamma = (const float*)d_in[6];
  const float* beta = (const float*)d_in[7];
  float* out = (float*)d_out;
  char* ws = (char*)d_ws;

  unsigned short* xT = (unsigned short*)(ws + 0);           // 2,359,296
  unsigned short* w_inb = (unsigned short*)(ws + 2359296);  // 786,432
  unsigned short* w_pwb = (unsigned short*)(ws + 3145728);  // 524,288
  unsigned char* qn = (unsigned char*)(ws + 3670016);       // 2,359,296 fp8 [bh][p][64]
  unsigned char* kn = (unsigned char*)(ws + 6029312);       // 2,359,296 fp8 [bh][p][64]
  unsigned short* vv = (unsigned short*)(ws + 8388608);     // 4,718,592 bf16 [bh][p][64]
  unsigned short* dwb = (unsigned short*)(ws + 13107200);   // 4,718,592 bf16
  float* lp = (float*)(ws + 17825792);                      // 442,368  [3][16][2304] fp32
  unsigned short* attnp = (unsigned short*)(ws + 18268160); // bf16 [3][16][2304][64] = 14,155,776
  float* pw = (float*)(ws + 32423936);                      // fp32 [2][512][2304] = 9,437,184

  k_prep<<<2848, 256, 0, stream>>>(x, w_in, w_pw, xT, w_inb, w_pwb);
  k_gemm_qkv<<<dim3(18, 24, 2), 256, 0, stream>>>(w_inb, xT, b_in, ss, qn, kn, vv);
  k_attn<<<dim3(16, 18, 3), 256, 0, stream>>>(qn, kn, vv, ss, attnp, lp);
  k_dwconv<<<dim3(16, 576), 256, 0, stream>>>(attnp, lp, w_dw, dwb);
  k_gemm2<<<dim3(36, 8, 2), 128, 0, stream>>>(w_pwb, dwb, pw, INNER_, S_, INNER_);
  k_ln_final<<<dim3(144, 2), 256, 0, stream>>>(pw, gamma, beta, x, out);
}